// Round 5
// baseline (1568.926 us; speedup 1.0000x reference)
//
#include <hip/hip_runtime.h>

typedef unsigned short u16;
typedef unsigned long long u64;
typedef __bf16 bf16x8 __attribute__((ext_vector_type(8)));
typedef float f32x4 __attribute__((ext_vector_type(4)));

#define T_STEPS 128
#define NB 256
#define HDIM 512
#define DIN_ 255
#define PACK_ 517
#define TN 32768  // T_STEPS*NB

__device__ __forceinline__ float b2f(u16 u) {
    union { unsigned int i; float f; } v; v.i = ((unsigned int)u) << 16; return v.f;
}
__device__ __forceinline__ u16 f2b(float f) {
    union { float f; unsigned int i; } v; v.f = f;
    unsigned int r = v.i + 0x7FFFu + ((v.i >> 16) & 1u);
    return (u16)(r >> 16);
}
__device__ __forceinline__ float sigm(float x) { return 1.f / (1.f + __expf(-x)); }
__device__ __forceinline__ float ftanh(float x) { return 2.f * sigm(2.f * x) - 1.f; }

// plain (cached) 16B load; vmcnt tracked manually via WAIT macros.
__device__ __forceinline__ bf16x8 ldx4(const u16* p) {
    f32x4 t;
    asm volatile("global_load_dwordx4 %0, %1, off" : "=v"(t) : "v"(p) : "memory");
    union { f32x4 f; bf16x8 b; } u; u.f = t; return u.b;
}
#define WAIT_VMCNT(N) asm volatile("s_waitcnt vmcnt(" #N ")" ::: "memory")
#define WAIT_LGKM0    asm volatile("s_waitcnt lgkmcnt(0)" ::: "memory")

// C[M x N] = act(A @ B^T + bias); B panel (64 x K) staged in LDS fragment-major,
// reused across MT m-tiles. grid (N/64, M/(64*MT)), block 256.
template<int DO_TANH, int K, int MT>
__global__ __launch_bounds__(256) void gemm_bt(const u16* __restrict__ A,
                                               const u16* __restrict__ B,
                                               const float* __restrict__ bias,
                                               u16* __restrict__ C, int N) {
    __shared__ u16 lds[64 * K];  // frag(row,kq) at u16 idx (kq*64+row)*8
    int n0 = blockIdx.x * 64;
    int w = threadIdx.x >> 6, l = threadIdx.x & 63;
    int la = l & 15, lb = l >> 4;
    for (int idx = threadIdx.x; idx < 8 * K; idx += 256) {  // 64*K/8 chunks of 16B
        int kq = idx >> 6, row = idx & 63;
        *(bf16x8*)(lds + (size_t)idx * 8) =
            *(const bf16x8*)(B + (size_t)(n0 + row) * K + kq * 8);
    }
    __syncthreads();
    const u16* bq[4];
    #pragma unroll
    for (int c = 0; c < 4; ++c) bq[c] = lds + ((size_t)lb * 64 + 16 * c + la) * 8;

    for (int mt = 0; mt < MT; ++mt) {
        int m0 = (blockIdx.y * MT + mt) * 64;
        int mw = m0 + 16 * w;
        const u16* Ap = A + (size_t)(mw + la) * K + 8 * lb;
        f32x4 acc[4] = {};
        #pragma unroll
        for (int k0 = 0; k0 < K; k0 += 32) {
            bf16x8 a = *(const bf16x8*)(Ap + k0);
            #pragma unroll
            for (int c = 0; c < 4; ++c)
                acc[c] = __builtin_amdgcn_mfma_f32_16x16x32_bf16(
                    a, *(const bf16x8*)(bq[c] + (size_t)k0 * 64), acc[c], 0, 0, 0);
        }
        #pragma unroll
        for (int c = 0; c < 4; ++c) {
            int n = n0 + 16 * c + la;
            float bv = bias[n];
            #pragma unroll
            for (int r = 0; r < 4; ++r) {
                int m = mw + 4 * lb + r;
                float v = acc[c][r] + bv;
                if (DO_TANH) v = ftanh(v);
                C[(size_t)m * N + n] = f2b(v);
            }
        }
    }
}

// Persistent GRU recurrence, 128 WGs = 8 batch groups (32 rows) x 16 col-slice WGs.
// Control plane is VERBATIM the R3-proven design (single group counter, per-wave
// lane-0 polls, asm atomics on the loc path, AGENT intrinsics otherwise).
// R5 change: the recurrence NO LONGER writes the fp32 packed `out` tensor.
// Theory: those 2048 scattered, never-64B-aligned dword stores per WG per step
// are partial-line writes -> write-allocate fills (L2/L3 RTT each); their drain
// (explicit vmcnt(0), or implicit via the poll's first atomic read sharing the
// in-order vmcnt counter) dominated the per-step critical path in ALL prior
// variants -- explaining why four different sync designs all timed ~8us/step.
// A separate coalesced expand_h kernel widens hs_b -> out[...,4:516] afterwards
// (h outputs become bf16-rounded: |h|<1 so extra error <= 0.004, well within
// the 0.085 threshold; the MLP heads already consumed bf16 h).
__global__ __launch_bounds__(256, 1) void gru_persist(
    const u16* __restrict__ h0b, const float* __restrict__ hx,
    const u16* __restrict__ whh_b, const float* __restrict__ bhh,
    const u16* __restrict__ gi_b,
    u16* __restrict__ hs_b, unsigned int* __restrict__ bar) {
    extern __shared__ u16 lds[];  // 98304 B weights + 2048 B pack
    __shared__ unsigned s_locv;
    const int tid = threadIdx.x;
    const int bid = blockIdx.x;
    const int g = bid & 7, s = bid >> 3;     // batch group, col slice
    const int ks = s * 32, m0 = g * 32;
    const int w = tid >> 6, l = tid & 63;
    const int la = l & 15, lb = l >> 4;
    const int rw = w >> 1, cw = w & 1;       // wave = (row half, col half)
    const int mw = m0 + 16 * rw;             // wave's batch-row base
    const int kc = ks + 16 * cw;             // wave's out-col base

    // publish this WG's XCD id (AGENT atomic into zeroed table -> acts as store)
    unsigned myx;
    asm volatile("s_getreg_b32 %0, hwreg(HW_REG_XCC_ID)" : "=s"(myx));
    myx = (myx & 15u) + 1u;
    unsigned int* tbl = bar + 512;  // byte offset 2048, 128 entries
    if (tid == 0)
        __hip_atomic_fetch_add(tbl + bid, myx, __ATOMIC_RELAXED,
                               __HIP_MEMORY_SCOPE_AGENT);

    // stage Whh slice -> LDS fragment-major: frag(row,kq) at u16 idx (kq*96+row)*8
    for (int idx = tid; idx < 6144; idx += 256) {
        int kq = idx / 96, row = idx - kq * 96;
        int gg = row >> 5, rr = row & 31;
        *(bf16x8*)(lds + (size_t)idx * 8) =
            *(const bf16x8*)(whh_b + (size_t)(gg * HDIM + ks + rr) * HDIM + kq * 8);
    }
    const u16* bq[3];
    #pragma unroll
    for (int c = 0; c < 3; ++c)
        bq[c] = lds + (size_t)(lb * 96 + c * 32 + 16 * cw + la) * 8;
    float bh[3];
    #pragma unroll
    for (int gg = 0; gg < 3; ++gg) bh[gg] = bhh[gg * HDIM + kc + la];
    float hp[4];
    #pragma unroll
    for (int r = 0; r < 4; ++r)
        hp[r] = hx[(size_t)(mw + 4 * lb + r) * PACK_ + 4 + kc + la];

    // placement detection (tid0): AGENT atomic-add-0 polls, guard-bounded.
    // All WGs see the same write-once values -> identical verdict.
    if (tid == 0) {
        unsigned vals[16];
        int guard = 0;
        bool ok;
        do {
            ok = true;
            #pragma unroll
            for (int k = 0; k < 16; ++k) {
                vals[k] = __hip_atomic_fetch_add(tbl + g + 8 * k, 0u,
                                                 __ATOMIC_RELAXED,
                                                 __HIP_MEMORY_SCOPE_AGENT);
                ok = ok && (vals[k] != 0u);
            }
            if (!ok) __builtin_amdgcn_s_sleep(8);
        } while (!ok && ++guard < (1 << 16));
        unsigned lv = ok ? 1u : 0u;
        #pragma unroll
        for (int k = 1; k < 16; ++k) lv &= (unsigned)(vals[k] == vals[0]);
        s_locv = lv;
    }
    u16* packbuf = lds + 49152 + w * 256;  // per-wave 16x16 u16 tile
    __syncthreads();
    const bool loc = (s_locv != 0);
    unsigned int* mybar = bar + g * 64;    // 256B-separated group counters

    for (int t = 0; t < T_STEPS; ++t) {
        const u16* gi_t = gi_b + (size_t)t * NB * 3 * HDIM;

        // gi prefetch (no cross-WG dependency; in flight during the poll wait)
        u16 giv[3][4];
        #pragma unroll
        for (int r = 0; r < 4; ++r) {
            const u16* gp = gi_t + (size_t)(mw + 4 * lb + r) * 1536 + kc + la;
            #pragma unroll
            for (int gg = 0; gg < 3; ++gg) giv[gg][r] = gp[gg * HDIM];
        }

        // wait for h[t-1]: 16 WG-flags per group per step. One poller per wave
        // (lane 0), result broadcast; atomic-add-0 at the SAME coherence point
        // as the producer's flag add.
        if (t > 0) {
            unsigned tgt = 16u * (unsigned)t;
            int guard = 0;
            for (;;) {
                unsigned v = 0;
                if (l == 0) {
                    if (loc)
                        asm volatile(
                            "global_atomic_add %0, %1, %2, off sc0\n\t"
                            "s_waitcnt vmcnt(0)"
                            : "=v"(v) : "v"(mybar), "v"(0u) : "memory");
                    else
                        v = __hip_atomic_fetch_add(mybar, 0u, __ATOMIC_RELAXED,
                                                   __HIP_MEMORY_SCOPE_AGENT);
                }
                v = (unsigned)__builtin_amdgcn_readfirstlane((int)v);
                if (v >= tgt || ++guard > (1 << 20)) break;
                __builtin_amdgcn_s_sleep(1);
            }
            asm volatile("" ::: "memory");  // no data-load hoisting above poll
        }

        // A-fragments: plain cached 16B loads (first touch is after the flag,
        // so any cache fill observes the producer's data)
        const u16* Ap = (t ? hs_b + (size_t)(t - 1) * NB * HDIM : h0b)
                        + (size_t)(mw + la) * HDIM + 8 * lb;
        bf16x8 a[16];
        #pragma unroll
        for (int kk = 0; kk < 16; ++kk) a[kk] = ldx4(Ap + 32 * kk);

        f32x4 acc[3] = {};
        WAIT_VMCNT(8);                       // a[0..7] landed (in-order count)
        __builtin_amdgcn_sched_barrier(0);   // rule #18
        #pragma unroll
        for (int kk = 0; kk < 8; ++kk) {
            #pragma unroll
            for (int c = 0; c < 3; ++c)
                acc[c] = __builtin_amdgcn_mfma_f32_16x16x32_bf16(
                    a[kk], *(const bf16x8*)(bq[c] + (size_t)kk * 3072), acc[c], 0, 0, 0);
        }
        WAIT_VMCNT(0);                       // a[8..15] landed
        __builtin_amdgcn_sched_barrier(0);
        #pragma unroll
        for (int kk = 8; kk < 16; ++kk) {
            #pragma unroll
            for (int c = 0; c < 3; ++c)
                acc[c] = __builtin_amdgcn_mfma_f32_16x16x32_bf16(
                    a[kk], *(const bf16x8*)(bq[c] + (size_t)kk * 3072), acc[c], 0, 0, 0);
        }

        // epilogue: gate math (fp32 carry in registers)
        float hnewv[4];
        #pragma unroll
        for (int r = 0; r < 4; ++r) {
            float rr2 = sigm(b2f(giv[0][r]) + acc[0][r] + bh[0]);
            float zz  = sigm(b2f(giv[1][r]) + acc[1][r] + bh[1]);
            float nn  = ftanh(b2f(giv[2][r]) + rr2 * (acc[2][r] + bh[2]));
            float hnew = (1.f - zz) * nn + zz * hp[r];
            hp[r] = hnew;
            hnewv[r] = hnew;
        }

        // pack h_new (bf16) into per-wave LDS tile [16 rows][16 cols]
        #pragma unroll
        for (int r = 0; r < 4; ++r) {
            float nbv = __shfl_xor(hnewv[r], 1, 64);
            if (!(la & 1)) {
                unsigned pk = (unsigned)f2b(hnewv[r]) | ((unsigned)f2b(nbv) << 16);
                *(unsigned*)(packbuf + (4 * lb + r) * 16 + la) = pk;
            }
        }
        WAIT_LGKM0;
        __builtin_amdgcn_sched_barrier(0);
        // one 16B store per lane (lanes 0..31): row = l>>1, 8-col chunk = l&1
        u16* hs_t = hs_b + (size_t)t * NB * HDIM;
        if (l < 32) {
            bf16x8 hv = *(const bf16x8*)(packbuf + (l >> 1) * 16 + 8 * (l & 1));
            union { bf16x8 b; f32x4 f; } u; u.b = hv;
            u16* sp = hs_t + (size_t)(mw + (l >> 1)) * HDIM + kc + 8 * (l & 1);
            if (loc) asm volatile("global_store_dwordx4 %0, %1, off"
                                  :: "v"(sp), "v"(u.f) : "memory");
            else     asm volatile("global_store_dwordx4 %0, %1, off sc0 sc1"
                                  :: "v"(sp), "v"(u.f) : "memory");
        }
        WAIT_VMCNT(0);     // own h stores acked at the coherence point
        __syncthreads();   // all 4 waves drained
        if (t < T_STEPS - 1 && tid == 0) {
            if (loc)
                asm volatile("global_atomic_add %0, %1, off"
                             :: "v"(mybar), "v"(1u) : "memory");
            else
                __hip_atomic_fetch_add(mybar, 1u, __ATOMIC_RELAXED,
                                       __HIP_MEMORY_SCOPE_AGENT);
        }
    }
}

// widen hs_b (bf16) -> out[...,4:4+H] (f32); both sides fully coalesced.
// one thread per 2 adjacent columns (u32 load, 2 dword stores).
__global__ void expand_h(const u16* __restrict__ hs, float* __restrict__ out) {
    int idx = blockIdx.x * 256 + threadIdx.x;
    if (idx >= TN * 256) return;
    int m = idx >> 8, kk = (idx & 255) * 2;
    unsigned pk = *(const unsigned*)(hs + (size_t)m * HDIM + kk);
    float* o = out + (size_t)m * PACK_ + 4 + kk;
    o[0] = b2f((u16)(pk & 0xFFFFu));
    o[1] = b2f((u16)(pk >> 16));
}

// one wave per row: out[row*517+off] = dot(X[row,:512], W[:512]) + b[0]
__global__ __launch_bounds__(256) void head_dot(const u16* __restrict__ X,
                                                const u16* __restrict__ W,
                                                const float* __restrict__ b,
                                                float* __restrict__ out, int off) {
    int wid = (int)((blockIdx.x * blockDim.x + threadIdx.x) >> 6);
    int l = threadIdx.x & 63;
    if (wid >= TN) return;
    bf16x8 xv = *(const bf16x8*)(X + (size_t)wid * HDIM + 8 * l);
    bf16x8 wv = *(const bf16x8*)(W + 8 * l);
    float s = 0.f;
    #pragma unroll
    for (int j = 0; j < 8; ++j) s += (float)xv[j] * (float)wv[j];
    #pragma unroll
    for (int d = 32; d; d >>= 1) s += __shfl_down(s, d, 64);
    if (l == 0) out[(size_t)wid * PACK_ + off] = s + b[0];
}

__global__ void prep_w(const float* __restrict__ Wih, const float* __restrict__ Whh,
                       const float* __restrict__ Wa0, const float* __restrict__ Wa1,
                       const float* __restrict__ Wloc, const float* __restrict__ Wc0,
                       const float* __restrict__ Wc1, const float* __restrict__ Wv,
                       const float* __restrict__ hx,
                       u16* Wih_b, u16* Whh_b, u16* Wa0_b, u16* Wa1_b,
                       u16* Wloc_b, u16* Wc0_b, u16* Wc1_b, u16* Wv_b,
                       float* h0f, u16* h0b) {
    int i = blockIdx.x * 256 + threadIdx.x;
    if (i < 1536 * 256) { int r = i >> 8, c = i & 255;
        Wih_b[i] = (c < DIN_) ? f2b(Wih[r * DIN_ + c]) : (u16)0; return; }
    i -= 1536 * 256;
    if (i < 1536 * 512) { Whh_b[i] = f2b(Whh[i]); return; } i -= 1536 * 512;
    if (i < 512 * 512) { Wa0_b[i] = f2b(Wa0[i]); return; } i -= 512 * 512;
    if (i < 512 * 512) { Wa1_b[i] = f2b(Wa1[i]); return; } i -= 512 * 512;
    if (i < 512 * 512) { Wc0_b[i] = f2b(Wc0[i]); return; } i -= 512 * 512;
    if (i < 512 * 512) { Wc1_b[i] = f2b(Wc1[i]); return; } i -= 512 * 512;
    if (i < 512) { Wloc_b[i] = f2b(Wloc[i]); return; } i -= 512;
    if (i < 512) { Wv_b[i] = f2b(Wv[i]); return; } i -= 512;
    if (i < NB * HDIM) { int n = i >> 9, k = i & 511;
        float v = hx[n * PACK_ + 4 + k]; h0f[i] = v; h0b[i] = f2b(v); return; }
}

// vectorized: each thread converts 8 contiguous f32 -> bf16x8 (zeroing d=255)
__global__ void prep_obs(const float* __restrict__ in, u16* __restrict__ obs) {
    int idx = blockIdx.x * 256 + threadIdx.x;
    if (idx >= TN * 32) return;
    int m = idx >> 5, j = idx & 31;
    const float* src = in + (size_t)m * 256 + 8 * j;
    union { u16 s[8]; uint4 u; } t;
    #pragma unroll
    for (int q = 0; q < 8; ++q) t.s[q] = f2b(src[q]);
    if (j == 31) t.s[7] = 0;  // d=255 is the actions column
    *(uint4*)(obs + (size_t)m * 256 + 8 * j) = t.u;
}

__global__ void finalize_out(const float* __restrict__ in, const float* __restrict__ eps,
                             const float* __restrict__ hx, const float* __restrict__ logstd,
                             float* __restrict__ out) {
    int m = blockIdx.x * 256 + threadIdx.x;
    if (m >= TN) return;
    int n = m & (NB - 1);
    float scale = __expf(logstd[0]);
    float loc = out[(size_t)m * PACK_ + 1];
    float act = in[(size_t)m * 256 + DIN_];
    float a = (act < 0.f) ? (loc + scale * eps[m]) : act;
    out[(size_t)m * PACK_ + 0] = a;
    out[(size_t)m * PACK_ + 2] = scale;
    out[(size_t)m * PACK_ + PACK_ - 1] = hx[n * PACK_ + PACK_ - 1];
}

__global__ void tail_copy(float* __restrict__ out) {
    int i = blockIdx.x * 256 + threadIdx.x;
    if (i >= NB * PACK_) return;
    out[(size_t)T_STEPS * NB * PACK_ + i] = out[(size_t)(T_STEPS - 1) * NB * PACK_ + i];
}

extern "C" void kernel_launch(void* const* d_in, const int* in_sizes, int n_in,
                              void* d_out, int out_size, void* d_ws, size_t ws_size,
                              hipStream_t stream) {
    const float* inputs = (const float*)d_in[0];
    const float* hx     = (const float*)d_in[1];
    const float* eps    = (const float*)d_in[2];
    const float* Wih    = (const float*)d_in[3];
    const float* Whh    = (const float*)d_in[4];
    const float* bih    = (const float*)d_in[5];
    const float* bhh    = (const float*)d_in[6];
    const float* Wa0    = (const float*)d_in[7];
    const float* ba0    = (const float*)d_in[8];
    const float* Wa1    = (const float*)d_in[9];
    const float* ba1    = (const float*)d_in[10];
    const float* Wloc   = (const float*)d_in[11];
    const float* bloc   = (const float*)d_in[12];
    const float* logstd = (const float*)d_in[13];
    const float* Wc0    = (const float*)d_in[14];
    const float* bc0    = (const float*)d_in[15];
    const float* Wc1    = (const float*)d_in[16];
    const float* bc1    = (const float*)d_in[17];
    const float* Wv     = (const float*)d_in[18];
    const float* bv     = (const float*)d_in[19];
    float* out = (float*)d_out;
    char* ws = (char*)d_ws;

    const size_t o_gi   = 0;                       // 100,663,296
    const size_t o_buf0 = 0;                       // alias (gi dead before MLPs)
    const size_t o_buf1 = 33554432;
    const size_t o_hs   = 100663296;               // 33,554,432
    const size_t o_obs  = o_hs + 33554432;         // 16,777,216
    const size_t o_whh  = o_obs + 16777216;        // 1,572,864
    const size_t o_wih  = o_whh + 1572864;         // 786,432
    const size_t o_wa0  = o_wih + 786432;
    const size_t o_wa1  = o_wa0 + 524288;
    const size_t o_wc0  = o_wa1 + 524288;
    const size_t o_wc1  = o_wc0 + 524288;
    const size_t o_wloc = o_wc1 + 524288;
    const size_t o_wv   = o_wloc + 1024;
    const size_t o_h0f  = o_wv + 1024;
    const size_t o_h0b  = o_h0f + 524288;
    const size_t o_bar  = o_h0b + 262144;          // 8 group counters + xcd table
    const size_t NEED   = o_bar + 4096;
    if (ws_size < NEED) return;

    u16*   gi_b   = (u16*)(ws + o_gi);
    u16*   buf0   = (u16*)(ws + o_buf0);
    u16*   buf1   = (u16*)(ws + o_buf1);
    u16*   hs_b   = (u16*)(ws + o_hs);
    u16*   obs_b  = (u16*)(ws + o_obs);
    u16*   whh_b  = (u16*)(ws + o_whh);
    u16*   wih_b  = (u16*)(ws + o_wih);
    u16*   wa0_b  = (u16*)(ws + o_wa0);
    u16*   wa1_b  = (u16*)(ws + o_wa1);
    u16*   wc0_b  = (u16*)(ws + o_wc0);
    u16*   wc1_b  = (u16*)(ws + o_wc1);
    u16*   wloc_b = (u16*)(ws + o_wloc);
    u16*   wv_b   = (u16*)(ws + o_wv);
    float* h0f    = (float*)(ws + o_h0f);
    u16*   h0b    = (u16*)(ws + o_h0b);
    unsigned int* bar = (unsigned int*)(ws + o_bar);

    static bool attr_set = false;
    if (!attr_set) {  // host-side attribute config, idempotent
        hipFuncSetAttribute((const void*)gru_persist,
                            hipFuncAttributeMaxDynamicSharedMemorySize, 102400);
        attr_set = true;
    }

    hipMemsetAsync(bar, 0, 4096, stream);  // flags + xcd table zeroed each call

    prep_w<<<9220, 256, 0, stream>>>(Wih, Whh, Wa0, Wa1, Wloc, Wc0, Wc1, Wv, hx,
                                     wih_b, whh_b, wa0_b, wa1_b, wloc_b, wc0_b, wc1_b, wv_b,
                                     h0f, h0b);
    prep_obs<<<4096, 256, 0, stream>>>(inputs, obs_b);

    // gi = obs_pad @ Wih_pad^T + bih   (M=32768, N=1536, K=256)
    gemm_bt<0, 256, 8><<<dim3(24, 64), 256, 0, stream>>>(obs_b, wih_b, bih, gi_b, 1536);

    // persistent recurrence: 128 WGs (8 groups x 16 slices), 102400 B dyn LDS
    gru_persist<<<128, 256, 102400, stream>>>(h0b, hx, whh_b, bhh, gi_b, hs_b, bar);

    // widen bf16 h -> fp32 packed out (coalesced bulk pass, off the sync path)
    expand_h<<<32768, 256, 0, stream>>>(hs_b, out);

    // actor MLP
    gemm_bt<1, 512, 8><<<dim3(8, 64), 256, 0, stream>>>(hs_b, wa0_b, ba0, buf0, 512);
    gemm_bt<1, 512, 8><<<dim3(8, 64), 256, 0, stream>>>(buf0, wa1_b, ba1, buf1, 512);
    head_dot<<<8192, 256, 0, stream>>>(buf1, wloc_b, bloc, out, 1);
    // critic MLP
    gemm_bt<1, 512, 8><<<dim3(8, 64), 256, 0, stream>>>(hs_b, wc0_b, bc0, buf0, 512);
    gemm_bt<1, 512, 8><<<dim3(8, 64), 256, 0, stream>>>(buf0, wc1_b, bc1, buf1, 512);
    head_dot<<<8192, 256, 0, stream>>>(buf1, wv_b, bv, out, 3);

    finalize_out<<<128, 256, 0, stream>>>(inputs, eps, hx, logstd, out);
    tail_copy<<<518, 256, 0, stream>>>(out);
}

// Round 6
// 1559.594 us; speedup vs baseline: 1.0060x; 1.0060x over previous
//
#include <hip/hip_runtime.h>

typedef unsigned short u16;
typedef unsigned long long u64;
typedef __bf16 bf16x8 __attribute__((ext_vector_type(8)));
typedef float f32x4 __attribute__((ext_vector_type(4)));

#define T_STEPS 128
#define NB 256
#define HDIM 512
#define DIN_ 255
#define PACK_ 517
#define TN 32768  // T_STEPS*NB

__device__ __forceinline__ float b2f(u16 u) {
    union { unsigned int i; float f; } v; v.i = ((unsigned int)u) << 16; return v.f;
}
__device__ __forceinline__ u16 f2b(float f) {
    union { float f; unsigned int i; } v; v.f = f;
    unsigned int r = v.i + 0x7FFFu + ((v.i >> 16) & 1u);
    return (u16)(r >> 16);
}
__device__ __forceinline__ float sigm(float x) { return 1.f / (1.f + __expf(-x)); }
__device__ __forceinline__ float ftanh(float x) { return 2.f * sigm(2.f * x) - 1.f; }

// plain (cached) 16B load; vmcnt tracked manually via WAIT macros.
__device__ __forceinline__ bf16x8 ldx4(const u16* p) {
    f32x4 t;
    asm volatile("global_load_dwordx4 %0, %1, off" : "=v"(t) : "v"(p) : "memory");
    union { f32x4 f; bf16x8 b; } u; u.f = t; return u.b;
}
#define WAIT_VMCNT(N) asm volatile("s_waitcnt vmcnt(" #N ")" ::: "memory")
#define WAIT_LGKM0    asm volatile("s_waitcnt lgkmcnt(0)" ::: "memory")

// C[M x N] = act(A @ B^T + bias); B panel (64 x K) staged in LDS fragment-major,
// reused across MT m-tiles. grid (N/64, M/(64*MT)), block 256.
template<int DO_TANH, int K, int MT>
__global__ __launch_bounds__(256) void gemm_bt(const u16* __restrict__ A,
                                               const u16* __restrict__ B,
                                               const float* __restrict__ bias,
                                               u16* __restrict__ C, int N) {
    __shared__ u16 lds[64 * K];  // frag(row,kq) at u16 idx (kq*64+row)*8
    int n0 = blockIdx.x * 64;
    int w = threadIdx.x >> 6, l = threadIdx.x & 63;
    int la = l & 15, lb = l >> 4;
    for (int idx = threadIdx.x; idx < 8 * K; idx += 256) {  // 64*K/8 chunks of 16B
        int kq = idx >> 6, row = idx & 63;
        *(bf16x8*)(lds + (size_t)idx * 8) =
            *(const bf16x8*)(B + (size_t)(n0 + row) * K + kq * 8);
    }
    __syncthreads();
    const u16* bq[4];
    #pragma unroll
    for (int c = 0; c < 4; ++c) bq[c] = lds + ((size_t)lb * 64 + 16 * c + la) * 8;

    for (int mt = 0; mt < MT; ++mt) {
        int m0 = (blockIdx.y * MT + mt) * 64;
        int mw = m0 + 16 * w;
        const u16* Ap = A + (size_t)(mw + la) * K + 8 * lb;
        f32x4 acc[4] = {};
        #pragma unroll
        for (int k0 = 0; k0 < K; k0 += 32) {
            bf16x8 a = *(const bf16x8*)(Ap + k0);
            #pragma unroll
            for (int c = 0; c < 4; ++c)
                acc[c] = __builtin_amdgcn_mfma_f32_16x16x32_bf16(
                    a, *(const bf16x8*)(bq[c] + (size_t)k0 * 64), acc[c], 0, 0, 0);
        }
        #pragma unroll
        for (int c = 0; c < 4; ++c) {
            int n = n0 + 16 * c + la;
            float bv = bias[n];
            #pragma unroll
            for (int r = 0; r < 4; ++r) {
                int m = mw + 4 * lb + r;
                float v = acc[c][r] + bv;
                if (DO_TANH) v = ftanh(v);
                C[(size_t)m * N + n] = f2b(v);
            }
        }
    }
}

// Persistent GRU recurrence, 128 WGs = 8 batch groups (32 rows) x 16 col-slice WGs.
// Sync semantics are VERBATIM R5 (passing): AGENT/loc atomics, per-wave lane-0
// poll, __syncthreads drain, bf16-only hs stores.
// R6 single-variable change: the poll loop HOT-SPINS (4 independent FMA chains,
// ~256cy) instead of s_sleep. Theory: the invariant ~8us/step floor across four
// sync designs -- and the PERVERSE trend that every traffic reduction made the
// kernel slower -- is DVFS down-clocking of a near-idle GPU (3.6% VALUBusy with
// all waves sleep-parked). Hot waves on 128 CUs hold SCLK up; if right, per-step
// time collapses to the analytic ~2-4k cycle chain.
__global__ __launch_bounds__(256, 1) void gru_persist(
    const u16* __restrict__ h0b, const float* __restrict__ hx,
    const u16* __restrict__ whh_b, const float* __restrict__ bhh,
    const u16* __restrict__ gi_b,
    u16* __restrict__ hs_b, unsigned int* __restrict__ bar) {
    extern __shared__ u16 lds[];  // 98304 B weights + 2048 B pack
    __shared__ unsigned s_locv;
    const int tid = threadIdx.x;
    const int bid = blockIdx.x;
    const int g = bid & 7, s = bid >> 3;     // batch group, col slice
    const int ks = s * 32, m0 = g * 32;
    const int w = tid >> 6, l = tid & 63;
    const int la = l & 15, lb = l >> 4;
    const int rw = w >> 1, cw = w & 1;       // wave = (row half, col half)
    const int mw = m0 + 16 * rw;             // wave's batch-row base
    const int kc = ks + 16 * cw;             // wave's out-col base

    // publish this WG's XCD id (AGENT atomic into zeroed table -> acts as store)
    unsigned myx;
    asm volatile("s_getreg_b32 %0, hwreg(HW_REG_XCC_ID)" : "=s"(myx));
    myx = (myx & 15u) + 1u;
    unsigned int* tbl = bar + 512;  // byte offset 2048, 128 entries
    if (tid == 0)
        __hip_atomic_fetch_add(tbl + bid, myx, __ATOMIC_RELAXED,
                               __HIP_MEMORY_SCOPE_AGENT);

    // stage Whh slice -> LDS fragment-major: frag(row,kq) at u16 idx (kq*96+row)*8
    for (int idx = tid; idx < 6144; idx += 256) {
        int kq = idx / 96, row = idx - kq * 96;
        int gg = row >> 5, rr = row & 31;
        *(bf16x8*)(lds + (size_t)idx * 8) =
            *(const bf16x8*)(whh_b + (size_t)(gg * HDIM + ks + rr) * HDIM + kq * 8);
    }
    const u16* bq[3];
    #pragma unroll
    for (int c = 0; c < 3; ++c)
        bq[c] = lds + (size_t)(lb * 96 + c * 32 + 16 * cw + la) * 8;
    float bh[3];
    #pragma unroll
    for (int gg = 0; gg < 3; ++gg) bh[gg] = bhh[gg * HDIM + kc + la];
    float hp[4];
    #pragma unroll
    for (int r = 0; r < 4; ++r)
        hp[r] = hx[(size_t)(mw + 4 * lb + r) * PACK_ + 4 + kc + la];

    // placement detection (tid0): AGENT atomic-add-0 polls, guard-bounded.
    if (tid == 0) {
        unsigned vals[16];
        int guard = 0;
        bool ok;
        do {
            ok = true;
            #pragma unroll
            for (int k = 0; k < 16; ++k) {
                vals[k] = __hip_atomic_fetch_add(tbl + g + 8 * k, 0u,
                                                 __ATOMIC_RELAXED,
                                                 __HIP_MEMORY_SCOPE_AGENT);
                ok = ok && (vals[k] != 0u);
            }
            if (!ok) __builtin_amdgcn_s_sleep(8);
        } while (!ok && ++guard < (1 << 16));
        unsigned lv = ok ? 1u : 0u;
        #pragma unroll
        for (int k = 1; k < 16; ++k) lv &= (unsigned)(vals[k] == vals[0]);
        s_locv = lv;
    }
    u16* packbuf = lds + 49152 + w * 256;  // per-wave 16x16 u16 tile
    __syncthreads();
    const bool loc = (s_locv != 0);
    unsigned int* mybar = bar + g * 64;    // 256B-separated group counters

    // hot-spin state (kept live across the whole kernel)
    float z0 = 1.0f + 1e-7f * (float)tid, z1 = z0 + 0.25f,
          z2 = z0 + 0.5f, z3 = z0 + 0.75f;

    for (int t = 0; t < T_STEPS; ++t) {
        const u16* gi_t = gi_b + (size_t)t * NB * 3 * HDIM;

        // gi prefetch (no cross-WG dependency; in flight during the poll wait)
        u16 giv[3][4];
        #pragma unroll
        for (int r = 0; r < 4; ++r) {
            const u16* gp = gi_t + (size_t)(mw + 4 * lb + r) * 1536 + kc + la;
            #pragma unroll
            for (int gg = 0; gg < 3; ++gg) giv[gg][r] = gp[gg * HDIM];
        }

        // wait for h[t-1]: 16 WG-flags per group per step. One poller per wave
        // (lane 0), result broadcast; atomic-add-0 at the SAME coherence point
        // as the producer's flag add. Between polls: HOT SPIN (no s_sleep) --
        // 4 independent FMA chains x 16 ~= 256cy, SIMD issuing every cycle.
        if (t > 0) {
            unsigned tgt = 16u * (unsigned)t;
            int guard = 0;
            for (;;) {
                unsigned v = 0;
                if (l == 0) {
                    if (loc)
                        asm volatile(
                            "global_atomic_add %0, %1, %2, off sc0\n\t"
                            "s_waitcnt vmcnt(0)"
                            : "=v"(v) : "v"(mybar), "v"(0u) : "memory");
                    else
                        v = __hip_atomic_fetch_add(mybar, 0u, __ATOMIC_RELAXED,
                                                   __HIP_MEMORY_SCOPE_AGENT);
                }
                v = (unsigned)__builtin_amdgcn_readfirstlane((int)v);
                if (v >= tgt || ++guard > (1 << 20)) break;
                #pragma unroll
                for (int q = 0; q < 16; ++q) {
                    z0 = __builtin_fmaf(z0, 1.0000001f, 0.0625f);
                    z1 = __builtin_fmaf(z1, 1.0000001f, 0.0625f);
                    z2 = __builtin_fmaf(z2, 1.0000001f, 0.0625f);
                    z3 = __builtin_fmaf(z3, 1.0000001f, 0.0625f);
                }
                asm volatile("" :: "v"(z0), "v"(z1), "v"(z2), "v"(z3));
            }
            asm volatile("" ::: "memory");  // no data-load hoisting above poll
        }

        // A-fragments: plain cached 16B loads (first touch is after the flag,
        // so any cache fill observes the producer's data)
        const u16* Ap = (t ? hs_b + (size_t)(t - 1) * NB * HDIM : h0b)
                        + (size_t)(mw + la) * HDIM + 8 * lb;
        bf16x8 a[16];
        #pragma unroll
        for (int kk = 0; kk < 16; ++kk) a[kk] = ldx4(Ap + 32 * kk);

        f32x4 acc[3] = {};
        WAIT_VMCNT(8);                       // a[0..7] landed (in-order count)
        __builtin_amdgcn_sched_barrier(0);   // rule #18
        #pragma unroll
        for (int kk = 0; kk < 8; ++kk) {
            #pragma unroll
            for (int c = 0; c < 3; ++c)
                acc[c] = __builtin_amdgcn_mfma_f32_16x16x32_bf16(
                    a[kk], *(const bf16x8*)(bq[c] + (size_t)kk * 3072), acc[c], 0, 0, 0);
        }
        WAIT_VMCNT(0);                       // a[8..15] landed
        __builtin_amdgcn_sched_barrier(0);
        #pragma unroll
        for (int kk = 8; kk < 16; ++kk) {
            #pragma unroll
            for (int c = 0; c < 3; ++c)
                acc[c] = __builtin_amdgcn_mfma_f32_16x16x32_bf16(
                    a[kk], *(const bf16x8*)(bq[c] + (size_t)kk * 3072), acc[c], 0, 0, 0);
        }

        // epilogue: gate math (fp32 carry in registers)
        float hnewv[4];
        #pragma unroll
        for (int r = 0; r < 4; ++r) {
            float rr2 = sigm(b2f(giv[0][r]) + acc[0][r] + bh[0]);
            float zz  = sigm(b2f(giv[1][r]) + acc[1][r] + bh[1]);
            float nn  = ftanh(b2f(giv[2][r]) + rr2 * (acc[2][r] + bh[2]));
            float hnew = (1.f - zz) * nn + zz * hp[r];
            hp[r] = hnew;
            hnewv[r] = hnew;
        }

        // pack h_new (bf16) into per-wave LDS tile [16 rows][16 cols]
        #pragma unroll
        for (int r = 0; r < 4; ++r) {
            float nbv = __shfl_xor(hnewv[r], 1, 64);
            if (!(la & 1)) {
                unsigned pk = (unsigned)f2b(hnewv[r]) | ((unsigned)f2b(nbv) << 16);
                *(unsigned*)(packbuf + (4 * lb + r) * 16 + la) = pk;
            }
        }
        WAIT_LGKM0;
        __builtin_amdgcn_sched_barrier(0);
        // one 16B store per lane (lanes 0..31): row = l>>1, 8-col chunk = l&1
        u16* hs_t = hs_b + (size_t)t * NB * HDIM;
        if (l < 32) {
            bf16x8 hv = *(const bf16x8*)(packbuf + (l >> 1) * 16 + 8 * (l & 1));
            union { bf16x8 b; f32x4 f; } u; u.b = hv;
            u16* sp = hs_t + (size_t)(mw + (l >> 1)) * HDIM + kc + 8 * (l & 1);
            if (loc) asm volatile("global_store_dwordx4 %0, %1, off"
                                  :: "v"(sp), "v"(u.f) : "memory");
            else     asm volatile("global_store_dwordx4 %0, %1, off sc0 sc1"
                                  :: "v"(sp), "v"(u.f) : "memory");
        }
        WAIT_VMCNT(0);     // own h stores acked at the coherence point
        __syncthreads();   // all 4 waves drained
        if (t < T_STEPS - 1 && tid == 0) {
            if (loc)
                asm volatile("global_atomic_add %0, %1, off"
                             :: "v"(mybar), "v"(1u) : "memory");
            else
                __hip_atomic_fetch_add(mybar, 1u, __ATOMIC_RELAXED,
                                       __HIP_MEMORY_SCOPE_AGENT);
        }
    }
}

// widen hs_b (bf16) -> out[...,4:4+H] (f32); both sides fully coalesced.
// one thread per 2 adjacent columns (u32 load, 2 dword stores).
__global__ void expand_h(const u16* __restrict__ hs, float* __restrict__ out) {
    int idx = blockIdx.x * 256 + threadIdx.x;
    if (idx >= TN * 256) return;
    int m = idx >> 8, kk = (idx & 255) * 2;
    unsigned pk = *(const unsigned*)(hs + (size_t)m * HDIM + kk);
    float* o = out + (size_t)m * PACK_ + 4 + kk;
    o[0] = b2f((u16)(pk & 0xFFFFu));
    o[1] = b2f((u16)(pk >> 16));
}

// one wave per row: out[row*517+off] = dot(X[row,:512], W[:512]) + b[0]
__global__ __launch_bounds__(256) void head_dot(const u16* __restrict__ X,
                                                const u16* __restrict__ W,
                                                const float* __restrict__ b,
                                                float* __restrict__ out, int off) {
    int wid = (int)((blockIdx.x * blockDim.x + threadIdx.x) >> 6);
    int l = threadIdx.x & 63;
    if (wid >= TN) return;
    bf16x8 xv = *(const bf16x8*)(X + (size_t)wid * HDIM + 8 * l);
    bf16x8 wv = *(const bf16x8*)(W + 8 * l);
    float s = 0.f;
    #pragma unroll
    for (int j = 0; j < 8; ++j) s += (float)xv[j] * (float)wv[j];
    #pragma unroll
    for (int d = 32; d; d >>= 1) s += __shfl_down(s, d, 64);
    if (l == 0) out[(size_t)wid * PACK_ + off] = s + b[0];
}

__global__ void prep_w(const float* __restrict__ Wih, const float* __restrict__ Whh,
                       const float* __restrict__ Wa0, const float* __restrict__ Wa1,
                       const float* __restrict__ Wloc, const float* __restrict__ Wc0,
                       const float* __restrict__ Wc1, const float* __restrict__ Wv,
                       const float* __restrict__ hx,
                       u16* Wih_b, u16* Whh_b, u16* Wa0_b, u16* Wa1_b,
                       u16* Wloc_b, u16* Wc0_b, u16* Wc1_b, u16* Wv_b,
                       float* h0f, u16* h0b) {
    int i = blockIdx.x * 256 + threadIdx.x;
    if (i < 1536 * 256) { int r = i >> 8, c = i & 255;
        Wih_b[i] = (c < DIN_) ? f2b(Wih[r * DIN_ + c]) : (u16)0; return; }
    i -= 1536 * 256;
    if (i < 1536 * 512) { Whh_b[i] = f2b(Whh[i]); return; } i -= 1536 * 512;
    if (i < 512 * 512) { Wa0_b[i] = f2b(Wa0[i]); return; } i -= 512 * 512;
    if (i < 512 * 512) { Wa1_b[i] = f2b(Wa1[i]); return; } i -= 512 * 512;
    if (i < 512 * 512) { Wc0_b[i] = f2b(Wc0[i]); return; } i -= 512 * 512;
    if (i < 512 * 512) { Wc1_b[i] = f2b(Wc1[i]); return; } i -= 512 * 512;
    if (i < 512) { Wloc_b[i] = f2b(Wloc[i]); return; } i -= 512;
    if (i < 512) { Wv_b[i] = f2b(Wv[i]); return; } i -= 512;
    if (i < NB * HDIM) { int n = i >> 9, k = i & 511;
        float v = hx[n * PACK_ + 4 + k]; h0f[i] = v; h0b[i] = f2b(v); return; }
}

// vectorized: each thread converts 8 contiguous f32 -> bf16x8 (zeroing d=255)
__global__ void prep_obs(const float* __restrict__ in, u16* __restrict__ obs) {
    int idx = blockIdx.x * 256 + threadIdx.x;
    if (idx >= TN * 32) return;
    int m = idx >> 5, j = idx & 31;
    const float* src = in + (size_t)m * 256 + 8 * j;
    union { u16 s[8]; uint4 u; } t;
    #pragma unroll
    for (int q = 0; q < 8; ++q) t.s[q] = f2b(src[q]);
    if (j == 31) t.s[7] = 0;  // d=255 is the actions column
    *(uint4*)(obs + (size_t)m * 256 + 8 * j) = t.u;
}

__global__ void finalize_out(const float* __restrict__ in, const float* __restrict__ eps,
                             const float* __restrict__ hx, const float* __restrict__ logstd,
                             float* __restrict__ out) {
    int m = blockIdx.x * 256 + threadIdx.x;
    if (m >= TN) return;
    int n = m & (NB - 1);
    float scale = __expf(logstd[0]);
    float loc = out[(size_t)m * PACK_ + 1];
    float act = in[(size_t)m * 256 + DIN_];
    float a = (act < 0.f) ? (loc + scale * eps[m]) : act;
    out[(size_t)m * PACK_ + 0] = a;
    out[(size_t)m * PACK_ + 2] = scale;
    out[(size_t)m * PACK_ + PACK_ - 1] = hx[n * PACK_ + PACK_ - 1];
}

__global__ void tail_copy(float* __restrict__ out) {
    int i = blockIdx.x * 256 + threadIdx.x;
    if (i >= NB * PACK_) return;
    out[(size_t)T_STEPS * NB * PACK_ + i] = out[(size_t)(T_STEPS - 1) * NB * PACK_ + i];
}

extern "C" void kernel_launch(void* const* d_in, const int* in_sizes, int n_in,
                              void* d_out, int out_size, void* d_ws, size_t ws_size,
                              hipStream_t stream) {
    const float* inputs = (const float*)d_in[0];
    const float* hx     = (const float*)d_in[1];
    const float* eps    = (const float*)d_in[2];
    const float* Wih    = (const float*)d_in[3];
    const float* Whh    = (const float*)d_in[4];
    const float* bih    = (const float*)d_in[5];
    const float* bhh    = (const float*)d_in[6];
    const float* Wa0    = (const float*)d_in[7];
    const float* ba0    = (const float*)d_in[8];
    const float* Wa1    = (const float*)d_in[9];
    const float* ba1    = (const float*)d_in[10];
    const float* Wloc   = (const float*)d_in[11];
    const float* bloc   = (const float*)d_in[12];
    const float* logstd = (const float*)d_in[13];
    const float* Wc0    = (const float*)d_in[14];
    const float* bc0    = (const float*)d_in[15];
    const float* Wc1    = (const float*)d_in[16];
    const float* bc1    = (const float*)d_in[17];
    const float* Wv     = (const float*)d_in[18];
    const float* bv     = (const float*)d_in[19];
    float* out = (float*)d_out;
    char* ws = (char*)d_ws;

    const size_t o_gi   = 0;                       // 100,663,296
    const size_t o_buf0 = 0;                       // alias (gi dead before MLPs)
    const size_t o_buf1 = 33554432;
    const size_t o_hs   = 100663296;               // 33,554,432
    const size_t o_obs  = o_hs + 33554432;         // 16,777,216
    const size_t o_whh  = o_obs + 16777216;        // 1,572,864
    const size_t o_wih  = o_whh + 1572864;         // 786,432
    const size_t o_wa0  = o_wih + 786432;
    const size_t o_wa1  = o_wa0 + 524288;
    const size_t o_wc0  = o_wa1 + 524288;
    const size_t o_wc1  = o_wc0 + 524288;
    const size_t o_wloc = o_wc1 + 524288;
    const size_t o_wv   = o_wloc + 1024;
    const size_t o_h0f  = o_wv + 1024;
    const size_t o_h0b  = o_h0f + 524288;
    const size_t o_bar  = o_h0b + 262144;          // 8 group counters + xcd table
    const size_t NEED   = o_bar + 4096;
    if (ws_size < NEED) return;

    u16*   gi_b   = (u16*)(ws + o_gi);
    u16*   buf0   = (u16*)(ws + o_buf0);
    u16*   buf1   = (u16*)(ws + o_buf1);
    u16*   hs_b   = (u16*)(ws + o_hs);
    u16*   obs_b  = (u16*)(ws + o_obs);
    u16*   whh_b  = (u16*)(ws + o_whh);
    u16*   wih_b  = (u16*)(ws + o_wih);
    u16*   wa0_b  = (u16*)(ws + o_wa0);
    u16*   wa1_b  = (u16*)(ws + o_wa1);
    u16*   wc0_b  = (u16*)(ws + o_wc0);
    u16*   wc1_b  = (u16*)(ws + o_wc1);
    u16*   wloc_b = (u16*)(ws + o_wloc);
    u16*   wv_b   = (u16*)(ws + o_wv);
    float* h0f    = (float*)(ws + o_h0f);
    u16*   h0b    = (u16*)(ws + o_h0b);
    unsigned int* bar = (unsigned int*)(ws + o_bar);

    static bool attr_set = false;
    if (!attr_set) {  // host-side attribute config, idempotent
        hipFuncSetAttribute((const void*)gru_persist,
                            hipFuncAttributeMaxDynamicSharedMemorySize, 102400);
        attr_set = true;
    }

    hipMemsetAsync(bar, 0, 4096, stream);  // flags + xcd table zeroed each call

    prep_w<<<9220, 256, 0, stream>>>(Wih, Whh, Wa0, Wa1, Wloc, Wc0, Wc1, Wv, hx,
                                     wih_b, whh_b, wa0_b, wa1_b, wloc_b, wc0_b, wc1_b, wv_b,
                                     h0f, h0b);
    prep_obs<<<4096, 256, 0, stream>>>(inputs, obs_b);

    // gi = obs_pad @ Wih_pad^T + bih   (M=32768, N=1536, K=256)
    gemm_bt<0, 256, 8><<<dim3(24, 64), 256, 0, stream>>>(obs_b, wih_b, bih, gi_b, 1536);

    // persistent recurrence: 128 WGs (8 groups x 16 slices), 102400 B dyn LDS
    gru_persist<<<128, 256, 102400, stream>>>(h0b, hx, whh_b, bhh, gi_b, hs_b, bar);

    // widen bf16 h -> fp32 packed out (coalesced bulk pass, off the sync path)
    expand_h<<<32768, 256, 0, stream>>>(hs_b, out);

    // actor MLP
    gemm_bt<1, 512, 8><<<dim3(8, 64), 256, 0, stream>>>(hs_b, wa0_b, ba0, buf0, 512);
    gemm_bt<1, 512, 8><<<dim3(8, 64), 256, 0, stream>>>(buf0, wa1_b, ba1, buf1, 512);
    head_dot<<<8192, 256, 0, stream>>>(buf1, wloc_b, bloc, out, 1);
    // critic MLP
    gemm_bt<1, 512, 8><<<dim3(8, 64), 256, 0, stream>>>(hs_b, wc0_b, bc0, buf0, 512);
    gemm_bt<1, 512, 8><<<dim3(8, 64), 256, 0, stream>>>(buf0, wc1_b, bc1, buf1, 512);
    head_dot<<<8192, 256, 0, stream>>>(buf1, wv_b, bv, out, 3);

    finalize_out<<<128, 256, 0, stream>>>(inputs, eps, hx, logstd, out);
    tail_copy<<<518, 256, 0, stream>>>(out);
}

// Round 7
// 1514.467 us; speedup vs baseline: 1.0360x; 1.0298x over previous
//
#include <hip/hip_runtime.h>

typedef unsigned short u16;
typedef unsigned long long u64;
typedef __bf16 bf16x8 __attribute__((ext_vector_type(8)));
typedef float f32x4 __attribute__((ext_vector_type(4)));

#define T_STEPS 128
#define NB 256
#define HDIM 512
#define DIN_ 255
#define PACK_ 517
#define TN 32768  // T_STEPS*NB

__device__ __forceinline__ float b2f(u16 u) {
    union { unsigned int i; float f; } v; v.i = ((unsigned int)u) << 16; return v.f;
}
__device__ __forceinline__ u16 f2b(float f) {
    union { float f; unsigned int i; } v; v.f = f;
    unsigned int r = v.i + 0x7FFFu + ((v.i >> 16) & 1u);
    return (u16)(r >> 16);
}
__device__ __forceinline__ float sigm(float x) { return 1.f / (1.f + __expf(-x)); }
__device__ __forceinline__ float ftanh(float x) { return 2.f * sigm(2.f * x) - 1.f; }

// plain (cached) 16B load; vmcnt tracked manually via WAIT macros.
__device__ __forceinline__ bf16x8 ldx4(const u16* p) {
    f32x4 t;
    asm volatile("global_load_dwordx4 %0, %1, off" : "=v"(t) : "v"(p) : "memory");
    union { f32x4 f; bf16x8 b; } u; u.f = t; return u.b;
}
#define WAIT_VMCNT(N) asm volatile("s_waitcnt vmcnt(" #N ")" ::: "memory")
#define WAIT_LGKM0    asm volatile("s_waitcnt lgkmcnt(0)" ::: "memory")

// C[M x N] = act(A @ B^T + bias); B panel (64 x K) staged in LDS fragment-major,
// reused across MT m-tiles. grid (N/64, M/(64*MT)), block 256.
template<int DO_TANH, int K, int MT>
__global__ __launch_bounds__(256) void gemm_bt(const u16* __restrict__ A,
                                               const u16* __restrict__ B,
                                               const float* __restrict__ bias,
                                               u16* __restrict__ C, int N) {
    __shared__ u16 lds[64 * K];  // frag(row,kq) at u16 idx (kq*64+row)*8
    int n0 = blockIdx.x * 64;
    int w = threadIdx.x >> 6, l = threadIdx.x & 63;
    int la = l & 15, lb = l >> 4;
    for (int idx = threadIdx.x; idx < 8 * K; idx += 256) {  // 64*K/8 chunks of 16B
        int kq = idx >> 6, row = idx & 63;
        *(bf16x8*)(lds + (size_t)idx * 8) =
            *(const bf16x8*)(B + (size_t)(n0 + row) * K + kq * 8);
    }
    __syncthreads();
    const u16* bq[4];
    #pragma unroll
    for (int c = 0; c < 4; ++c) bq[c] = lds + ((size_t)lb * 64 + 16 * c + la) * 8;

    for (int mt = 0; mt < MT; ++mt) {
        int m0 = (blockIdx.y * MT + mt) * 64;
        int mw = m0 + 16 * w;
        const u16* Ap = A + (size_t)(mw + la) * K + 8 * lb;
        f32x4 acc[4] = {};
        #pragma unroll
        for (int k0 = 0; k0 < K; k0 += 32) {
            bf16x8 a = *(const bf16x8*)(Ap + k0);
            #pragma unroll
            for (int c = 0; c < 4; ++c)
                acc[c] = __builtin_amdgcn_mfma_f32_16x16x32_bf16(
                    a, *(const bf16x8*)(bq[c] + (size_t)k0 * 64), acc[c], 0, 0, 0);
        }
        #pragma unroll
        for (int c = 0; c < 4; ++c) {
            int n = n0 + 16 * c + la;
            float bv = bias[n];
            #pragma unroll
            for (int r = 0; r < 4; ++r) {
                int m = mw + 4 * lb + r;
                float v = acc[c][r] + bv;
                if (DO_TANH) v = ftanh(v);
                C[(size_t)m * N + n] = f2b(v);
            }
        }
    }
}

// Persistent GRU recurrence, 128 WGs = 8 batch groups (32 rows) x 16 col-slice WGs.
// R7 sync redesign. Evidence from R6: hot-spin left VALUBusy at 3.7% -> poll
// loop body rarely runs -> waves sit in s_waitcnt on the poll atomic's return.
// Mechanism: ALL pollers and producers of a group RMW ONE cache line; its
// service queue never drains; every atomic (incl. the producer's flag add!)
// queues behind ~64 others -> ~10-20k cy RT. Fix:
//   1. per-WG flag lines (256B apart): producer adds to its OWN line.
//   2. only wave 0 polls: lanes 0..15 issue ONE vector atomic across the 16
//      group lines (parallel service); waves 1..3 wait at __syncthreads.
//   3. exponential backoff between failed rounds -> ~<=2 in-flight RMW/line.
// Primitives are the R3/R5-proven set: asm plain/sc0 atomics on loc path,
// AGENT intrinsics otherwise, __syncthreads. No WORKGROUP scope, no LDS relay.
__global__ __launch_bounds__(256, 1) void gru_persist(
    const u16* __restrict__ h0b, const float* __restrict__ hx,
    const u16* __restrict__ whh_b, const float* __restrict__ bhh,
    const u16* __restrict__ gi_b,
    u16* __restrict__ hs_b, unsigned int* __restrict__ bar) {
    extern __shared__ u16 lds[];  // 98304 B weights + 2048 B pack
    __shared__ unsigned s_locv;
    const int tid = threadIdx.x;
    const int bid = blockIdx.x;
    const int g = bid & 7, s = bid >> 3;     // batch group, col slice
    const int ks = s * 32, m0 = g * 32;
    const int w = tid >> 6, l = tid & 63;
    const int la = l & 15, lb = l >> 4;
    const int rw = w >> 1, cw = w & 1;       // wave = (row half, col half)
    const int mw = m0 + 16 * rw;             // wave's batch-row base
    const int kc = ks + 16 * cw;             // wave's out-col base

    // publish this WG's XCD id (AGENT atomic into zeroed table -> acts as store)
    unsigned myx;
    asm volatile("s_getreg_b32 %0, hwreg(HW_REG_XCC_ID)" : "=s"(myx));
    myx = (myx & 15u) + 1u;
    unsigned int* tbl = bar + 8192;  // after 32KB of flag lines; 128 entries
    if (tid == 0)
        __hip_atomic_fetch_add(tbl + bid, myx, __ATOMIC_RELAXED,
                               __HIP_MEMORY_SCOPE_AGENT);

    // stage Whh slice -> LDS fragment-major: frag(row,kq) at u16 idx (kq*96+row)*8
    for (int idx = tid; idx < 6144; idx += 256) {
        int kq = idx / 96, row = idx - kq * 96;
        int gg = row >> 5, rr = row & 31;
        *(bf16x8*)(lds + (size_t)idx * 8) =
            *(const bf16x8*)(whh_b + (size_t)(gg * HDIM + ks + rr) * HDIM + kq * 8);
    }
    const u16* bq[3];
    #pragma unroll
    for (int c = 0; c < 3; ++c)
        bq[c] = lds + (size_t)(lb * 96 + c * 32 + 16 * cw + la) * 8;
    float bh[3];
    #pragma unroll
    for (int gg = 0; gg < 3; ++gg) bh[gg] = bhh[gg * HDIM + kc + la];
    float hp[4];
    #pragma unroll
    for (int r = 0; r < 4; ++r)
        hp[r] = hx[(size_t)(mw + 4 * lb + r) * PACK_ + 4 + kc + la];

    // placement detection (tid0): AGENT atomic-add-0 polls, guard-bounded.
    if (tid == 0) {
        unsigned vals[16];
        int guard = 0;
        bool ok;
        do {
            ok = true;
            #pragma unroll
            for (int k = 0; k < 16; ++k) {
                vals[k] = __hip_atomic_fetch_add(tbl + g + 8 * k, 0u,
                                                 __ATOMIC_RELAXED,
                                                 __HIP_MEMORY_SCOPE_AGENT);
                ok = ok && (vals[k] != 0u);
            }
            if (!ok) __builtin_amdgcn_s_sleep(8);
        } while (!ok && ++guard < (1 << 16));
        unsigned lv = ok ? 1u : 0u;
        #pragma unroll
        for (int k = 1; k < 16; ++k) lv &= (unsigned)(vals[k] == vals[0]);
        s_locv = lv;
    }
    u16* packbuf = lds + 49152 + w * 256;  // per-wave 16x16 u16 tile
    __syncthreads();
    const bool loc = (s_locv != 0);
    // per-WG flag lines, 256B apart. Own line for producing; group lines for polling.
    unsigned int* myline = bar + (g * 16 + s) * 64;
    unsigned int* pline  = bar + (g * 16 + (l & 15)) * 64;

    for (int t = 0; t < T_STEPS; ++t) {
        const u16* gi_t = gi_b + (size_t)t * NB * 3 * HDIM;

        // gi prefetch (no cross-WG dependency; in flight during the poll wait)
        u16 giv[3][4];
        #pragma unroll
        for (int r = 0; r < 4; ++r) {
            const u16* gp = gi_t + (size_t)(mw + 4 * lb + r) * 1536 + kc + la;
            #pragma unroll
            for (int gg = 0; gg < 3; ++gg) giv[gg][r] = gp[gg * HDIM];
        }

        // wait for h[t-1]: per-WG counters must all reach t. Wave 0 polls all
        // 16 lines with one VECTOR atomic round (lanes 0..15); backoff between
        // failed rounds. Waves 1..3 wait at the barrier below.
        if (t > 0) {
            if (w == 0) {
                int guard = 0, delay = 32;
                for (;;) {
                    bool okl = true;
                    if (l < 16) {
                        unsigned v;
                        if (loc)
                            asm volatile(
                                "global_atomic_add %0, %1, %2, off sc0\n\t"
                                "s_waitcnt vmcnt(0)"
                                : "=v"(v) : "v"(pline), "v"(0u) : "memory");
                        else
                            v = __hip_atomic_fetch_add(pline, 0u, __ATOMIC_RELAXED,
                                                       __HIP_MEMORY_SCOPE_AGENT);
                        okl = ((int)v >= t);
                    }
                    if (__all(okl) || ++guard > (1 << 14)) break;
                    // exponential-backoff burn (dependent FMA chain)
                    float z = (float)delay;
                    for (int q = 0; q < delay; ++q)
                        z = __builtin_fmaf(z, 1.0000001f, 0.0625f);
                    asm volatile("" :: "v"(z));
                    delay = delay < 2048 ? delay * 2 : 2048;
                }
            }
            __syncthreads();  // release waves 1..3 once wave 0 saw all flags
            asm volatile("" ::: "memory");  // no data-load hoisting above sync
        }

        // A-fragments: plain cached 16B loads (first touch is after the flag,
        // so any cache fill observes the producer's data)
        const u16* Ap = (t ? hs_b + (size_t)(t - 1) * NB * HDIM : h0b)
                        + (size_t)(mw + la) * HDIM + 8 * lb;
        bf16x8 a[16];
        #pragma unroll
        for (int kk = 0; kk < 16; ++kk) a[kk] = ldx4(Ap + 32 * kk);

        f32x4 acc[3] = {};
        WAIT_VMCNT(8);                       // a[0..7] landed (in-order count)
        __builtin_amdgcn_sched_barrier(0);   // rule #18
        #pragma unroll
        for (int kk = 0; kk < 8; ++kk) {
            #pragma unroll
            for (int c = 0; c < 3; ++c)
                acc[c] = __builtin_amdgcn_mfma_f32_16x16x32_bf16(
                    a[kk], *(const bf16x8*)(bq[c] + (size_t)kk * 3072), acc[c], 0, 0, 0);
        }
        WAIT_VMCNT(0);                       // a[8..15] landed
        __builtin_amdgcn_sched_barrier(0);
        #pragma unroll
        for (int kk = 8; kk < 16; ++kk) {
            #pragma unroll
            for (int c = 0; c < 3; ++c)
                acc[c] = __builtin_amdgcn_mfma_f32_16x16x32_bf16(
                    a[kk], *(const bf16x8*)(bq[c] + (size_t)kk * 3072), acc[c], 0, 0, 0);
        }

        // epilogue: gate math (fp32 carry in registers)
        float hnewv[4];
        #pragma unroll
        for (int r = 0; r < 4; ++r) {
            float rr2 = sigm(b2f(giv[0][r]) + acc[0][r] + bh[0]);
            float zz  = sigm(b2f(giv[1][r]) + acc[1][r] + bh[1]);
            float nn  = ftanh(b2f(giv[2][r]) + rr2 * (acc[2][r] + bh[2]));
            float hnew = (1.f - zz) * nn + zz * hp[r];
            hp[r] = hnew;
            hnewv[r] = hnew;
        }

        // pack h_new (bf16) into per-wave LDS tile [16 rows][16 cols]
        #pragma unroll
        for (int r = 0; r < 4; ++r) {
            float nbv = __shfl_xor(hnewv[r], 1, 64);
            if (!(la & 1)) {
                unsigned pk = (unsigned)f2b(hnewv[r]) | ((unsigned)f2b(nbv) << 16);
                *(unsigned*)(packbuf + (4 * lb + r) * 16 + la) = pk;
            }
        }
        WAIT_LGKM0;
        __builtin_amdgcn_sched_barrier(0);
        // one 16B store per lane (lanes 0..31): row = l>>1, 8-col chunk = l&1
        u16* hs_t = hs_b + (size_t)t * NB * HDIM;
        if (l < 32) {
            bf16x8 hv = *(const bf16x8*)(packbuf + (l >> 1) * 16 + 8 * (l & 1));
            union { bf16x8 b; f32x4 f; } u; u.b = hv;
            u16* sp = hs_t + (size_t)(mw + (l >> 1)) * HDIM + kc + 8 * (l & 1);
            if (loc) asm volatile("global_store_dwordx4 %0, %1, off"
                                  :: "v"(sp), "v"(u.f) : "memory");
            else     asm volatile("global_store_dwordx4 %0, %1, off sc0 sc1"
                                  :: "v"(sp), "v"(u.f) : "memory");
        }
        WAIT_VMCNT(0);     // own h stores acked at the coherence point
        __syncthreads();   // all 4 waves drained
        if (t < T_STEPS - 1 && tid == 0) {
            if (loc)
                asm volatile("global_atomic_add %0, %1, off"
                             :: "v"(myline), "v"(1u) : "memory");
            else
                __hip_atomic_fetch_add(myline, 1u, __ATOMIC_RELAXED,
                                       __HIP_MEMORY_SCOPE_AGENT);
        }
    }
}

// widen hs_b (bf16) -> out[...,4:4+H] (f32); both sides fully coalesced.
// one thread per 2 adjacent columns (u32 load, 2 dword stores).
__global__ void expand_h(const u16* __restrict__ hs, float* __restrict__ out) {
    int idx = blockIdx.x * 256 + threadIdx.x;
    if (idx >= TN * 256) return;
    int m = idx >> 8, kk = (idx & 255) * 2;
    unsigned pk = *(const unsigned*)(hs + (size_t)m * HDIM + kk);
    float* o = out + (size_t)m * PACK_ + 4 + kk;
    o[0] = b2f((u16)(pk & 0xFFFFu));
    o[1] = b2f((u16)(pk >> 16));
}

// one wave per row: out[row*517+off] = dot(X[row,:512], W[:512]) + b[0]
__global__ __launch_bounds__(256) void head_dot(const u16* __restrict__ X,
                                                const u16* __restrict__ W,
                                                const float* __restrict__ b,
                                                float* __restrict__ out, int off) {
    int wid = (int)((blockIdx.x * blockDim.x + threadIdx.x) >> 6);
    int l = threadIdx.x & 63;
    if (wid >= TN) return;
    bf16x8 xv = *(const bf16x8*)(X + (size_t)wid * HDIM + 8 * l);
    bf16x8 wv = *(const bf16x8*)(W + 8 * l);
    float s = 0.f;
    #pragma unroll
    for (int j = 0; j < 8; ++j) s += (float)xv[j] * (float)wv[j];
    #pragma unroll
    for (int d = 32; d; d >>= 1) s += __shfl_down(s, d, 64);
    if (l == 0) out[(size_t)wid * PACK_ + off] = s + b[0];
}

__global__ void prep_w(const float* __restrict__ Wih, const float* __restrict__ Whh,
                       const float* __restrict__ Wa0, const float* __restrict__ Wa1,
                       const float* __restrict__ Wloc, const float* __restrict__ Wc0,
                       const float* __restrict__ Wc1, const float* __restrict__ Wv,
                       const float* __restrict__ hx,
                       u16* Wih_b, u16* Whh_b, u16* Wa0_b, u16* Wa1_b,
                       u16* Wloc_b, u16* Wc0_b, u16* Wc1_b, u16* Wv_b,
                       float* h0f, u16* h0b) {
    int i = blockIdx.x * 256 + threadIdx.x;
    if (i < 1536 * 256) { int r = i >> 8, c = i & 255;
        Wih_b[i] = (c < DIN_) ? f2b(Wih[r * DIN_ + c]) : (u16)0; return; }
    i -= 1536 * 256;
    if (i < 1536 * 512) { Whh_b[i] = f2b(Whh[i]); return; } i -= 1536 * 512;
    if (i < 512 * 512) { Wa0_b[i] = f2b(Wa0[i]); return; } i -= 512 * 512;
    if (i < 512 * 512) { Wa1_b[i] = f2b(Wa1[i]); return; } i -= 512 * 512;
    if (i < 512 * 512) { Wc0_b[i] = f2b(Wc0[i]); return; } i -= 512 * 512;
    if (i < 512 * 512) { Wc1_b[i] = f2b(Wc1[i]); return; } i -= 512 * 512;
    if (i < 512) { Wloc_b[i] = f2b(Wloc[i]); return; } i -= 512;
    if (i < 512) { Wv_b[i] = f2b(Wv[i]); return; } i -= 512;
    if (i < NB * HDIM) { int n = i >> 9, k = i & 511;
        float v = hx[n * PACK_ + 4 + k]; h0f[i] = v; h0b[i] = f2b(v); return; }
}

// vectorized: each thread converts 8 contiguous f32 -> bf16x8 (zeroing d=255)
__global__ void prep_obs(const float* __restrict__ in, u16* __restrict__ obs) {
    int idx = blockIdx.x * 256 + threadIdx.x;
    if (idx >= TN * 32) return;
    int m = idx >> 5, j = idx & 31;
    const float* src = in + (size_t)m * 256 + 8 * j;
    union { u16 s[8]; uint4 u; } t;
    #pragma unroll
    for (int q = 0; q < 8; ++q) t.s[q] = f2b(src[q]);
    if (j == 31) t.s[7] = 0;  // d=255 is the actions column
    *(uint4*)(obs + (size_t)m * 256 + 8 * j) = t.u;
}

__global__ void finalize_out(const float* __restrict__ in, const float* __restrict__ eps,
                             const float* __restrict__ hx, const float* __restrict__ logstd,
                             float* __restrict__ out) {
    int m = blockIdx.x * 256 + threadIdx.x;
    if (m >= TN) return;
    int n = m & (NB - 1);
    float scale = __expf(logstd[0]);
    float loc = out[(size_t)m * PACK_ + 1];
    float act = in[(size_t)m * 256 + DIN_];
    float a = (act < 0.f) ? (loc + scale * eps[m]) : act;
    out[(size_t)m * PACK_ + 0] = a;
    out[(size_t)m * PACK_ + 2] = scale;
    out[(size_t)m * PACK_ + PACK_ - 1] = hx[n * PACK_ + PACK_ - 1];
}

__global__ void tail_copy(float* __restrict__ out) {
    int i = blockIdx.x * 256 + threadIdx.x;
    if (i >= NB * PACK_) return;
    out[(size_t)T_STEPS * NB * PACK_ + i] = out[(size_t)(T_STEPS - 1) * NB * PACK_ + i];
}

extern "C" void kernel_launch(void* const* d_in, const int* in_sizes, int n_in,
                              void* d_out, int out_size, void* d_ws, size_t ws_size,
                              hipStream_t stream) {
    const float* inputs = (const float*)d_in[0];
    const float* hx     = (const float*)d_in[1];
    const float* eps    = (const float*)d_in[2];
    const float* Wih    = (const float*)d_in[3];
    const float* Whh    = (const float*)d_in[4];
    const float* bih    = (const float*)d_in[5];
    const float* bhh    = (const float*)d_in[6];
    const float* Wa0    = (const float*)d_in[7];
    const float* ba0    = (const float*)d_in[8];
    const float* Wa1    = (const float*)d_in[9];
    const float* ba1    = (const float*)d_in[10];
    const float* Wloc   = (const float*)d_in[11];
    const float* bloc   = (const float*)d_in[12];
    const float* logstd = (const float*)d_in[13];
    const float* Wc0    = (const float*)d_in[14];
    const float* bc0    = (const float*)d_in[15];
    const float* Wc1    = (const float*)d_in[16];
    const float* bc1    = (const float*)d_in[17];
    const float* Wv     = (const float*)d_in[18];
    const float* bv     = (const float*)d_in[19];
    float* out = (float*)d_out;
    char* ws = (char*)d_ws;

    const size_t o_gi   = 0;                       // 100,663,296
    const size_t o_buf0 = 0;                       // alias (gi dead before MLPs)
    const size_t o_buf1 = 33554432;
    const size_t o_hs   = 100663296;               // 33,554,432
    const size_t o_obs  = o_hs + 33554432;         // 16,777,216
    const size_t o_whh  = o_obs + 16777216;        // 1,572,864
    const size_t o_wih  = o_whh + 1572864;         // 786,432
    const size_t o_wa0  = o_wih + 786432;
    const size_t o_wa1  = o_wa0 + 524288;
    const size_t o_wc0  = o_wa1 + 524288;
    const size_t o_wc1  = o_wc0 + 524288;
    const size_t o_wloc = o_wc1 + 524288;
    const size_t o_wv   = o_wloc + 1024;
    const size_t o_h0f  = o_wv + 1024;
    const size_t o_h0b  = o_h0f + 524288;
    const size_t o_bar  = o_h0b + 262144;  // 128 flag lines (32KB) + xcd table
    const size_t NEED   = o_bar + 36864;
    if (ws_size < NEED) return;

    u16*   gi_b   = (u16*)(ws + o_gi);
    u16*   buf0   = (u16*)(ws + o_buf0);
    u16*   buf1   = (u16*)(ws + o_buf1);
    u16*   hs_b   = (u16*)(ws + o_hs);
    u16*   obs_b  = (u16*)(ws + o_obs);
    u16*   whh_b  = (u16*)(ws + o_whh);
    u16*   wih_b  = (u16*)(ws + o_wih);
    u16*   wa0_b  = (u16*)(ws + o_wa0);
    u16*   wa1_b  = (u16*)(ws + o_wa1);
    u16*   wc0_b  = (u16*)(ws + o_wc0);
    u16*   wc1_b  = (u16*)(ws + o_wc1);
    u16*   wloc_b = (u16*)(ws + o_wloc);
    u16*   wv_b   = (u16*)(ws + o_wv);
    float* h0f    = (float*)(ws + o_h0f);
    u16*   h0b    = (u16*)(ws + o_h0b);
    unsigned int* bar = (unsigned int*)(ws + o_bar);

    static bool attr_set = false;
    if (!attr_set) {  // host-side attribute config, idempotent
        hipFuncSetAttribute((const void*)gru_persist,
                            hipFuncAttributeMaxDynamicSharedMemorySize, 102400);
        attr_set = true;
    }

    hipMemsetAsync(bar, 0, 36864, stream);  // flag lines + xcd table zeroed

    prep_w<<<9220, 256, 0, stream>>>(Wih, Whh, Wa0, Wa1, Wloc, Wc0, Wc1, Wv, hx,
                                     wih_b, whh_b, wa0_b, wa1_b, wloc_b, wc0_b, wc1_b, wv_b,
                                     h0f, h0b);
    prep_obs<<<4096, 256, 0, stream>>>(inputs, obs_b);

    // gi = obs_pad @ Wih_pad^T + bih   (M=32768, N=1536, K=256)
    gemm_bt<0, 256, 8><<<dim3(24, 64), 256, 0, stream>>>(obs_b, wih_b, bih, gi_b, 1536);

    // persistent recurrence: 128 WGs (8 groups x 16 slices), 102400 B dyn LDS
    gru_persist<<<128, 256, 102400, stream>>>(h0b, hx, whh_b, bhh, gi_b, hs_b, bar);

    // widen bf16 h -> fp32 packed out (coalesced bulk pass, off the sync path)
    expand_h<<<32768, 256, 0, stream>>>(hs_b, out);

    // actor MLP
    gemm_bt<1, 512, 8><<<dim3(8, 64), 256, 0, stream>>>(hs_b, wa0_b, ba0, buf0, 512);
    gemm_bt<1, 512, 8><<<dim3(8, 64), 256, 0, stream>>>(buf0, wa1_b, ba1, buf1, 512);
    head_dot<<<8192, 256, 0, stream>>>(buf1, wloc_b, bloc, out, 1);
    // critic MLP
    gemm_bt<1, 512, 8><<<dim3(8, 64), 256, 0, stream>>>(hs_b, wc0_b, bc0, buf0, 512);
    gemm_bt<1, 512, 8><<<dim3(8, 64), 256, 0, stream>>>(buf0, wc1_b, bc1, buf1, 512);
    head_dot<<<8192, 256, 0, stream>>>(buf1, wv_b, bv, out, 3);

    finalize_out<<<128, 256, 0, stream>>>(inputs, eps, hx, logstd, out);
    tail_copy<<<518, 256, 0, stream>>>(out);
}

// Round 8
// 1498.332 us; speedup vs baseline: 1.0471x; 1.0108x over previous
//
#include <hip/hip_runtime.h>

typedef unsigned short u16;
typedef unsigned long long u64;
typedef __bf16 bf16x8 __attribute__((ext_vector_type(8)));
typedef float f32x4 __attribute__((ext_vector_type(4)));

#define T_STEPS 128
#define NB 256
#define HDIM 512
#define DIN_ 255
#define PACK_ 517
#define TN 32768  // T_STEPS*NB

__device__ __forceinline__ float b2f(u16 u) {
    union { unsigned int i; float f; } v; v.i = ((unsigned int)u) << 16; return v.f;
}
__device__ __forceinline__ u16 f2b(float f) {
    union { float f; unsigned int i; } v; v.f = f;
    unsigned int r = v.i + 0x7FFFu + ((v.i >> 16) & 1u);
    return (u16)(r >> 16);
}
__device__ __forceinline__ float sigm(float x) { return 1.f / (1.f + __expf(-x)); }
__device__ __forceinline__ float ftanh(float x) { return 2.f * sigm(2.f * x) - 1.f; }

// plain (cached) 16B load; vmcnt tracked manually via WAIT macros.
__device__ __forceinline__ bf16x8 ldx4(const u16* p) {
    f32x4 t;
    asm volatile("global_load_dwordx4 %0, %1, off" : "=v"(t) : "v"(p) : "memory");
    union { f32x4 f; bf16x8 b; } u; u.f = t; return u.b;
}
#define WAIT_VMCNT(N) asm volatile("s_waitcnt vmcnt(" #N ")" ::: "memory")
#define WAIT_LGKM0    asm volatile("s_waitcnt lgkmcnt(0)" ::: "memory")

// C[M x N] = act(A @ B^T + bias); B panel (64 x K) staged in LDS fragment-major,
// reused across MT m-tiles. grid (N/64, M/(64*MT)), block 256.
template<int DO_TANH, int K, int MT>
__global__ __launch_bounds__(256) void gemm_bt(const u16* __restrict__ A,
                                               const u16* __restrict__ B,
                                               const float* __restrict__ bias,
                                               u16* __restrict__ C, int N) {
    __shared__ u16 lds[64 * K];  // frag(row,kq) at u16 idx (kq*64+row)*8
    int n0 = blockIdx.x * 64;
    int w = threadIdx.x >> 6, l = threadIdx.x & 63;
    int la = l & 15, lb = l >> 4;
    for (int idx = threadIdx.x; idx < 8 * K; idx += 256) {  // 64*K/8 chunks of 16B
        int kq = idx >> 6, row = idx & 63;
        *(bf16x8*)(lds + (size_t)idx * 8) =
            *(const bf16x8*)(B + (size_t)(n0 + row) * K + kq * 8);
    }
    __syncthreads();
    const u16* bq[4];
    #pragma unroll
    for (int c = 0; c < 4; ++c) bq[c] = lds + ((size_t)lb * 64 + 16 * c + la) * 8;

    for (int mt = 0; mt < MT; ++mt) {
        int m0 = (blockIdx.y * MT + mt) * 64;
        int mw = m0 + 16 * w;
        const u16* Ap = A + (size_t)(mw + la) * K + 8 * lb;
        f32x4 acc[4] = {};
        #pragma unroll
        for (int k0 = 0; k0 < K; k0 += 32) {
            bf16x8 a = *(const bf16x8*)(Ap + k0);
            #pragma unroll
            for (int c = 0; c < 4; ++c)
                acc[c] = __builtin_amdgcn_mfma_f32_16x16x32_bf16(
                    a, *(const bf16x8*)(bq[c] + (size_t)k0 * 64), acc[c], 0, 0, 0);
        }
        #pragma unroll
        for (int c = 0; c < 4; ++c) {
            int n = n0 + 16 * c + la;
            float bv = bias[n];
            #pragma unroll
            for (int r = 0; r < 4; ++r) {
                int m = mw + 4 * lb + r;
                float v = acc[c][r] + bv;
                if (DO_TANH) v = ftanh(v);
                C[(size_t)m * N + n] = f2b(v);
            }
        }
    }
}

// Persistent GRU recurrence + heater WGs.
// R8 evidence chain: R7 counters give per-step cycles from MfmaUtil (~6300cy)
// vs wall 8.4us -> effective SCLK ~750 MHz. The chip idles (3.7% VALU, 94% of
// wave-cycles parked in s_waitcnt/s_barrier) -> power governor down-clocks ~3x.
// That single mechanism explains all six identical sync designs AND the perverse
// "less traffic -> slower" trend (more idle -> lower clock).
// Fix: WGs 0..127 = sync/compute role, BYTE-IDENTICAL to R7 (passing).
//      WGs 128..255 = heaters on the idle half: dependent-FMA burn, poll a
//      'done' line (atomic LOAD, no RMW, own cache line), guard-bounded exit.
// Heaters share nothing with the sync path -> no deadlock possible.
__global__ __launch_bounds__(256, 1) void gru_persist(
    const u16* __restrict__ h0b, const float* __restrict__ hx,
    const u16* __restrict__ whh_b, const float* __restrict__ bhh,
    const u16* __restrict__ gi_b,
    u16* __restrict__ hs_b, unsigned int* __restrict__ bar) {
    extern __shared__ u16 lds[];  // 98304 B weights + 2048 B pack
    __shared__ unsigned s_locv;
    const int tid = threadIdx.x;
    const int bid = blockIdx.x;

    if (bid >= 128) {
        // ---- heater role: keep the clock up on the otherwise-idle CUs ----
        unsigned int* done = bar + 8448;  // byte 33792, own cache line
        float z0 = 1.0f + 1e-7f * (float)tid, z1 = z0 + 0.3f,
              z2 = z0 + 0.6f, z3 = z0 + 0.9f;
        int guard = 0;
        for (;;) {
            #pragma unroll
            for (int q = 0; q < 256; ++q) {  // 1024 FMA insts ~ 2048 cy
                z0 = __builtin_fmaf(z0, 1.0000001f, 0.0625f);
                z1 = __builtin_fmaf(z1, 1.0000001f, 0.0625f);
                z2 = __builtin_fmaf(z2, 1.0000001f, 0.0625f);
                z3 = __builtin_fmaf(z3, 1.0000001f, 0.0625f);
            }
            asm volatile("" :: "v"(z0), "v"(z1), "v"(z2), "v"(z3));
            unsigned d = __hip_atomic_load(done, __ATOMIC_RELAXED,
                                           __HIP_MEMORY_SCOPE_AGENT);
            if (d >= 8u || ++guard > (1 << 12)) break;
        }
        return;
    }

    // ---- sync/compute role: byte-identical to R7 ----
    const int g = bid & 7, s = bid >> 3;     // batch group, col slice
    const int ks = s * 32, m0 = g * 32;
    const int w = tid >> 6, l = tid & 63;
    const int la = l & 15, lb = l >> 4;
    const int rw = w >> 1, cw = w & 1;       // wave = (row half, col half)
    const int mw = m0 + 16 * rw;             // wave's batch-row base
    const int kc = ks + 16 * cw;             // wave's out-col base

    // publish this WG's XCD id (AGENT atomic into zeroed table -> acts as store)
    unsigned myx;
    asm volatile("s_getreg_b32 %0, hwreg(HW_REG_XCC_ID)" : "=s"(myx));
    myx = (myx & 15u) + 1u;
    unsigned int* tbl = bar + 8192;  // after 32KB of flag lines; 128 entries
    if (tid == 0)
        __hip_atomic_fetch_add(tbl + bid, myx, __ATOMIC_RELAXED,
                               __HIP_MEMORY_SCOPE_AGENT);

    // stage Whh slice -> LDS fragment-major: frag(row,kq) at u16 idx (kq*96+row)*8
    for (int idx = tid; idx < 6144; idx += 256) {
        int kq = idx / 96, row = idx - kq * 96;
        int gg = row >> 5, rr = row & 31;
        *(bf16x8*)(lds + (size_t)idx * 8) =
            *(const bf16x8*)(whh_b + (size_t)(gg * HDIM + ks + rr) * HDIM + kq * 8);
    }
    const u16* bq[3];
    #pragma unroll
    for (int c = 0; c < 3; ++c)
        bq[c] = lds + (size_t)(lb * 96 + c * 32 + 16 * cw + la) * 8;
    float bh[3];
    #pragma unroll
    for (int gg = 0; gg < 3; ++gg) bh[gg] = bhh[gg * HDIM + kc + la];
    float hp[4];
    #pragma unroll
    for (int r = 0; r < 4; ++r)
        hp[r] = hx[(size_t)(mw + 4 * lb + r) * PACK_ + 4 + kc + la];

    // placement detection (tid0): AGENT atomic-add-0 polls, guard-bounded.
    if (tid == 0) {
        unsigned vals[16];
        int guard = 0;
        bool ok;
        do {
            ok = true;
            #pragma unroll
            for (int k = 0; k < 16; ++k) {
                vals[k] = __hip_atomic_fetch_add(tbl + g + 8 * k, 0u,
                                                 __ATOMIC_RELAXED,
                                                 __HIP_MEMORY_SCOPE_AGENT);
                ok = ok && (vals[k] != 0u);
            }
            if (!ok) __builtin_amdgcn_s_sleep(8);
        } while (!ok && ++guard < (1 << 16));
        unsigned lv = ok ? 1u : 0u;
        #pragma unroll
        for (int k = 1; k < 16; ++k) lv &= (unsigned)(vals[k] == vals[0]);
        s_locv = lv;
    }
    u16* packbuf = lds + 49152 + w * 256;  // per-wave 16x16 u16 tile
    __syncthreads();
    const bool loc = (s_locv != 0);
    // per-WG flag lines, 256B apart. Own line for producing; group lines for polling.
    unsigned int* myline = bar + (g * 16 + s) * 64;
    unsigned int* pline  = bar + (g * 16 + (l & 15)) * 64;

    for (int t = 0; t < T_STEPS; ++t) {
        const u16* gi_t = gi_b + (size_t)t * NB * 3 * HDIM;

        // gi prefetch (no cross-WG dependency; in flight during the poll wait)
        u16 giv[3][4];
        #pragma unroll
        for (int r = 0; r < 4; ++r) {
            const u16* gp = gi_t + (size_t)(mw + 4 * lb + r) * 1536 + kc + la;
            #pragma unroll
            for (int gg = 0; gg < 3; ++gg) giv[gg][r] = gp[gg * HDIM];
        }

        // wait for h[t-1]: per-WG counters must all reach t. Wave 0 polls all
        // 16 lines with one VECTOR atomic round (lanes 0..15); backoff between
        // failed rounds. Waves 1..3 wait at the barrier below.
        if (t > 0) {
            if (w == 0) {
                int guard = 0, delay = 32;
                for (;;) {
                    bool okl = true;
                    if (l < 16) {
                        unsigned v;
                        if (loc)
                            asm volatile(
                                "global_atomic_add %0, %1, %2, off sc0\n\t"
                                "s_waitcnt vmcnt(0)"
                                : "=v"(v) : "v"(pline), "v"(0u) : "memory");
                        else
                            v = __hip_atomic_fetch_add(pline, 0u, __ATOMIC_RELAXED,
                                                       __HIP_MEMORY_SCOPE_AGENT);
                        okl = ((int)v >= t);
                    }
                    if (__all(okl) || ++guard > (1 << 14)) break;
                    // exponential-backoff burn (dependent FMA chain)
                    float z = (float)delay;
                    for (int q = 0; q < delay; ++q)
                        z = __builtin_fmaf(z, 1.0000001f, 0.0625f);
                    asm volatile("" :: "v"(z));
                    delay = delay < 2048 ? delay * 2 : 2048;
                }
            }
            __syncthreads();  // release waves 1..3 once wave 0 saw all flags
            asm volatile("" ::: "memory");  // no data-load hoisting above sync
        }

        // A-fragments: plain cached 16B loads (first touch is after the flag,
        // so any cache fill observes the producer's data)
        const u16* Ap = (t ? hs_b + (size_t)(t - 1) * NB * HDIM : h0b)
                        + (size_t)(mw + la) * HDIM + 8 * lb;
        bf16x8 a[16];
        #pragma unroll
        for (int kk = 0; kk < 16; ++kk) a[kk] = ldx4(Ap + 32 * kk);

        f32x4 acc[3] = {};
        WAIT_VMCNT(8);                       // a[0..7] landed (in-order count)
        __builtin_amdgcn_sched_barrier(0);   // rule #18
        #pragma unroll
        for (int kk = 0; kk < 8; ++kk) {
            #pragma unroll
            for (int c = 0; c < 3; ++c)
                acc[c] = __builtin_amdgcn_mfma_f32_16x16x32_bf16(
                    a[kk], *(const bf16x8*)(bq[c] + (size_t)kk * 3072), acc[c], 0, 0, 0);
        }
        WAIT_VMCNT(0);                       // a[8..15] landed
        __builtin_amdgcn_sched_barrier(0);
        #pragma unroll
        for (int kk = 8; kk < 16; ++kk) {
            #pragma unroll
            for (int c = 0; c < 3; ++c)
                acc[c] = __builtin_amdgcn_mfma_f32_16x16x32_bf16(
                    a[kk], *(const bf16x8*)(bq[c] + (size_t)kk * 3072), acc[c], 0, 0, 0);
        }

        // epilogue: gate math (fp32 carry in registers)
        float hnewv[4];
        #pragma unroll
        for (int r = 0; r < 4; ++r) {
            float rr2 = sigm(b2f(giv[0][r]) + acc[0][r] + bh[0]);
            float zz  = sigm(b2f(giv[1][r]) + acc[1][r] + bh[1]);
            float nn  = ftanh(b2f(giv[2][r]) + rr2 * (acc[2][r] + bh[2]));
            float hnew = (1.f - zz) * nn + zz * hp[r];
            hp[r] = hnew;
            hnewv[r] = hnew;
        }

        // pack h_new (bf16) into per-wave LDS tile [16 rows][16 cols]
        #pragma unroll
        for (int r = 0; r < 4; ++r) {
            float nbv = __shfl_xor(hnewv[r], 1, 64);
            if (!(la & 1)) {
                unsigned pk = (unsigned)f2b(hnewv[r]) | ((unsigned)f2b(nbv) << 16);
                *(unsigned*)(packbuf + (4 * lb + r) * 16 + la) = pk;
            }
        }
        WAIT_LGKM0;
        __builtin_amdgcn_sched_barrier(0);
        // one 16B store per lane (lanes 0..31): row = l>>1, 8-col chunk = l&1
        u16* hs_t = hs_b + (size_t)t * NB * HDIM;
        if (l < 32) {
            bf16x8 hv = *(const bf16x8*)(packbuf + (l >> 1) * 16 + 8 * (l & 1));
            union { bf16x8 b; f32x4 f; } u; u.b = hv;
            u16* sp = hs_t + (size_t)(mw + (l >> 1)) * HDIM + kc + 8 * (l & 1);
            if (loc) asm volatile("global_store_dwordx4 %0, %1, off"
                                  :: "v"(sp), "v"(u.f) : "memory");
            else     asm volatile("global_store_dwordx4 %0, %1, off sc0 sc1"
                                  :: "v"(sp), "v"(u.f) : "memory");
        }
        WAIT_VMCNT(0);     // own h stores acked at the coherence point
        __syncthreads();   // all 4 waves drained
        if (t < T_STEPS - 1 && tid == 0) {
            if (loc)
                asm volatile("global_atomic_add %0, %1, off"
                             :: "v"(myline), "v"(1u) : "memory");
            else
                __hip_atomic_fetch_add(myline, 1u, __ATOMIC_RELAXED,
                                       __HIP_MEMORY_SCOPE_AGENT);
        }
    }

    // group finished: slice-0 WG bumps the heater 'done' counter
    if (s == 0 && tid == 0)
        __hip_atomic_fetch_add(bar + 8448, 1u, __ATOMIC_RELAXED,
                               __HIP_MEMORY_SCOPE_AGENT);
}

// widen hs_b (bf16) -> out[...,4:4+H] (f32); both sides fully coalesced.
// one thread per 2 adjacent columns (u32 load, 2 dword stores).
__global__ void expand_h(const u16* __restrict__ hs, float* __restrict__ out) {
    int idx = blockIdx.x * 256 + threadIdx.x;
    if (idx >= TN * 256) return;
    int m = idx >> 8, kk = (idx & 255) * 2;
    unsigned pk = *(const unsigned*)(hs + (size_t)m * HDIM + kk);
    float* o = out + (size_t)m * PACK_ + 4 + kk;
    o[0] = b2f((u16)(pk & 0xFFFFu));
    o[1] = b2f((u16)(pk >> 16));
}

// one wave per row: out[row*517+off] = dot(X[row,:512], W[:512]) + b[0]
__global__ __launch_bounds__(256) void head_dot(const u16* __restrict__ X,
                                                const u16* __restrict__ W,
                                                const float* __restrict__ b,
                                                float* __restrict__ out, int off) {
    int wid = (int)((blockIdx.x * blockDim.x + threadIdx.x) >> 6);
    int l = threadIdx.x & 63;
    if (wid >= TN) return;
    bf16x8 xv = *(const bf16x8*)(X + (size_t)wid * HDIM + 8 * l);
    bf16x8 wv = *(const bf16x8*)(W + 8 * l);
    float s = 0.f;
    #pragma unroll
    for (int j = 0; j < 8; ++j) s += (float)xv[j] * (float)wv[j];
    #pragma unroll
    for (int d = 32; d; d >>= 1) s += __shfl_down(s, d, 64);
    if (l == 0) out[(size_t)wid * PACK_ + off] = s + b[0];
}

__global__ void prep_w(const float* __restrict__ Wih, const float* __restrict__ Whh,
                       const float* __restrict__ Wa0, const float* __restrict__ Wa1,
                       const float* __restrict__ Wloc, const float* __restrict__ Wc0,
                       const float* __restrict__ Wc1, const float* __restrict__ Wv,
                       const float* __restrict__ hx,
                       u16* Wih_b, u16* Whh_b, u16* Wa0_b, u16* Wa1_b,
                       u16* Wloc_b, u16* Wc0_b, u16* Wc1_b, u16* Wv_b,
                       float* h0f, u16* h0b) {
    int i = blockIdx.x * 256 + threadIdx.x;
    if (i < 1536 * 256) { int r = i >> 8, c = i & 255;
        Wih_b[i] = (c < DIN_) ? f2b(Wih[r * DIN_ + c]) : (u16)0; return; }
    i -= 1536 * 256;
    if (i < 1536 * 512) { Whh_b[i] = f2b(Whh[i]); return; } i -= 1536 * 512;
    if (i < 512 * 512) { Wa0_b[i] = f2b(Wa0[i]); return; } i -= 512 * 512;
    if (i < 512 * 512) { Wa1_b[i] = f2b(Wa1[i]); return; } i -= 512 * 512;
    if (i < 512 * 512) { Wc0_b[i] = f2b(Wc0[i]); return; } i -= 512 * 512;
    if (i < 512 * 512) { Wc1_b[i] = f2b(Wc1[i]); return; } i -= 512 * 512;
    if (i < 512) { Wloc_b[i] = f2b(Wloc[i]); return; } i -= 512;
    if (i < 512) { Wv_b[i] = f2b(Wv[i]); return; } i -= 512;
    if (i < NB * HDIM) { int n = i >> 9, k = i & 511;
        float v = hx[n * PACK_ + 4 + k]; h0f[i] = v; h0b[i] = f2b(v); return; }
}

// vectorized: each thread converts 8 contiguous f32 -> bf16x8 (zeroing d=255)
__global__ void prep_obs(const float* __restrict__ in, u16* __restrict__ obs) {
    int idx = blockIdx.x * 256 + threadIdx.x;
    if (idx >= TN * 32) return;
    int m = idx >> 5, j = idx & 31;
    const float* src = in + (size_t)m * 256 + 8 * j;
    union { u16 s[8]; uint4 u; } t;
    #pragma unroll
    for (int q = 0; q < 8; ++q) t.s[q] = f2b(src[q]);
    if (j == 31) t.s[7] = 0;  // d=255 is the actions column
    *(uint4*)(obs + (size_t)m * 256 + 8 * j) = t.u;
}

__global__ void finalize_out(const float* __restrict__ in, const float* __restrict__ eps,
                             const float* __restrict__ hx, const float* __restrict__ logstd,
                             float* __restrict__ out) {
    int m = blockIdx.x * 256 + threadIdx.x;
    if (m >= TN) return;
    int n = m & (NB - 1);
    float scale = __expf(logstd[0]);
    float loc = out[(size_t)m * PACK_ + 1];
    float act = in[(size_t)m * 256 + DIN_];
    float a = (act < 0.f) ? (loc + scale * eps[m]) : act;
    out[(size_t)m * PACK_ + 0] = a;
    out[(size_t)m * PACK_ + 2] = scale;
    out[(size_t)m * PACK_ + PACK_ - 1] = hx[n * PACK_ + PACK_ - 1];
}

__global__ void tail_copy(float* __restrict__ out) {
    int i = blockIdx.x * 256 + threadIdx.x;
    if (i >= NB * PACK_) return;
    out[(size_t)T_STEPS * NB * PACK_ + i] = out[(size_t)(T_STEPS - 1) * NB * PACK_ + i];
}

extern "C" void kernel_launch(void* const* d_in, const int* in_sizes, int n_in,
                              void* d_out, int out_size, void* d_ws, size_t ws_size,
                              hipStream_t stream) {
    const float* inputs = (const float*)d_in[0];
    const float* hx     = (const float*)d_in[1];
    const float* eps    = (const float*)d_in[2];
    const float* Wih    = (const float*)d_in[3];
    const float* Whh    = (const float*)d_in[4];
    const float* bih    = (const float*)d_in[5];
    const float* bhh    = (const float*)d_in[6];
    const float* Wa0    = (const float*)d_in[7];
    const float* ba0    = (const float*)d_in[8];
    const float* Wa1    = (const float*)d_in[9];
    const float* ba1    = (const float*)d_in[10];
    const float* Wloc   = (const float*)d_in[11];
    const float* bloc   = (const float*)d_in[12];
    const float* logstd = (const float*)d_in[13];
    const float* Wc0    = (const float*)d_in[14];
    const float* bc0    = (const float*)d_in[15];
    const float* Wc1    = (const float*)d_in[16];
    const float* bc1    = (const float*)d_in[17];
    const float* Wv     = (const float*)d_in[18];
    const float* bv     = (const float*)d_in[19];
    float* out = (float*)d_out;
    char* ws = (char*)d_ws;

    const size_t o_gi   = 0;                       // 100,663,296
    const size_t o_buf0 = 0;                       // alias (gi dead before MLPs)
    const size_t o_buf1 = 33554432;
    const size_t o_hs   = 100663296;               // 33,554,432
    const size_t o_obs  = o_hs + 33554432;         // 16,777,216
    const size_t o_whh  = o_obs + 16777216;        // 1,572,864
    const size_t o_wih  = o_whh + 1572864;         // 786,432
    const size_t o_wa0  = o_wih + 786432;
    const size_t o_wa1  = o_wa0 + 524288;
    const size_t o_wc0  = o_wa1 + 524288;
    const size_t o_wc1  = o_wc0 + 524288;
    const size_t o_wloc = o_wc1 + 524288;
    const size_t o_wv   = o_wloc + 1024;
    const size_t o_h0f  = o_wv + 1024;
    const size_t o_h0b  = o_h0f + 524288;
    const size_t o_bar  = o_h0b + 262144;  // flag lines + xcd table + done
    const size_t NEED   = o_bar + 36864;
    if (ws_size < NEED) return;

    u16*   gi_b   = (u16*)(ws + o_gi);
    u16*   buf0   = (u16*)(ws + o_buf0);
    u16*   buf1   = (u16*)(ws + o_buf1);
    u16*   hs_b   = (u16*)(ws + o_hs);
    u16*   obs_b  = (u16*)(ws + o_obs);
    u16*   whh_b  = (u16*)(ws + o_whh);
    u16*   wih_b  = (u16*)(ws + o_wih);
    u16*   wa0_b  = (u16*)(ws + o_wa0);
    u16*   wa1_b  = (u16*)(ws + o_wa1);
    u16*   wc0_b  = (u16*)(ws + o_wc0);
    u16*   wc1_b  = (u16*)(ws + o_wc1);
    u16*   wloc_b = (u16*)(ws + o_wloc);
    u16*   wv_b   = (u16*)(ws + o_wv);
    float* h0f    = (float*)(ws + o_h0f);
    u16*   h0b    = (u16*)(ws + o_h0b);
    unsigned int* bar = (unsigned int*)(ws + o_bar);

    static bool attr_set = false;
    if (!attr_set) {  // host-side attribute config, idempotent
        hipFuncSetAttribute((const void*)gru_persist,
                            hipFuncAttributeMaxDynamicSharedMemorySize, 102400);
        attr_set = true;
    }

    hipMemsetAsync(bar, 0, 36864, stream);  // flag lines + xcd table + done zeroed

    prep_w<<<9220, 256, 0, stream>>>(Wih, Whh, Wa0, Wa1, Wloc, Wc0, Wc1, Wv, hx,
                                     wih_b, whh_b, wa0_b, wa1_b, wloc_b, wc0_b, wc1_b, wv_b,
                                     h0f, h0b);
    prep_obs<<<4096, 256, 0, stream>>>(inputs, obs_b);

    // gi = obs_pad @ Wih_pad^T + bih   (M=32768, N=1536, K=256)
    gemm_bt<0, 256, 8><<<dim3(24, 64), 256, 0, stream>>>(obs_b, wih_b, bih, gi_b, 1536);

    // persistent recurrence: 128 sync WGs + 128 heater WGs (1 WG/CU)
    gru_persist<<<256, 256, 102400, stream>>>(h0b, hx, whh_b, bhh, gi_b, hs_b, bar);

    // widen bf16 h -> fp32 packed out (coalesced bulk pass, off the sync path)
    expand_h<<<32768, 256, 0, stream>>>(hs_b, out);

    // actor MLP
    gemm_bt<1, 512, 8><<<dim3(8, 64), 256, 0, stream>>>(hs_b, wa0_b, ba0, buf0, 512);
    gemm_bt<1, 512, 8><<<dim3(8, 64), 256, 0, stream>>>(buf0, wa1_b, ba1, buf1, 512);
    head_dot<<<8192, 256, 0, stream>>>(buf1, wloc_b, bloc, out, 1);
    // critic MLP
    gemm_bt<1, 512, 8><<<dim3(8, 64), 256, 0, stream>>>(hs_b, wc0_b, bc0, buf0, 512);
    gemm_bt<1, 512, 8><<<dim3(8, 64), 256, 0, stream>>>(buf0, wc1_b, bc1, buf1, 512);
    head_dot<<<8192, 256, 0, stream>>>(buf1, wv_b, bv, out, 3);

    finalize_out<<<128, 256, 0, stream>>>(inputs, eps, hx, logstd, out);
    tail_copy<<<518, 256, 0, stream>>>(out);
}